// Round 1
// baseline (12980.315 us; speedup 1.0000x reference)
//
#include <hip/hip_runtime.h>

// Problem constants (from reference)
#define NUM_USERS 50000
#define NUM_ITEMS 50000
#define NUM_CATS  500
#define D         64
#define N_LAYERS  3
#define N_EDGES   500000
#define NNZ_G     1000000
#define NNZ_GX    2000000
#define BATCH     8192
#define N_NODES   (NUM_USERS + NUM_ITEMS)

// degree accumulation: degree[tu[e]] += 1, degree[NUM_USERS+ti[e]] += 1
__global__ void deg_kernel(const int* __restrict__ tu, const int* __restrict__ ti,
                           float* __restrict__ deg) {
    int e = blockIdx.x * blockDim.x + threadIdx.x;
    if (e >= N_EDGES) return;
    unsafeAtomicAdd(deg + tu[e], 1.0f);
    unsafeAtomicAdd(deg + NUM_USERS + ti[e], 1.0f);
}

__global__ void dinv_kernel(float* __restrict__ deg) {
    int n = blockIdx.x * blockDim.x + threadIdx.x;
    if (n < N_NODES) deg[n] = 1.0f / (deg[n] + 1e-9f);
}

// out[r*64 + d] += v * x[c*64 + d], 16 threads per edge, float4 per thread
__global__ void spmm_g_kernel(const int* __restrict__ rows, const int* __restrict__ cols,
                              const float* __restrict__ vals, const float* __restrict__ x,
                              float* __restrict__ out) {
    int tid = blockIdx.x * blockDim.x + threadIdx.x;
    int e = tid >> 4;
    int q = tid & 15;
    if (e >= NNZ_G) return;
    int r = rows[e], c = cols[e];
    float v = vals[e];
    const float4 xv = *(const float4*)(x + (size_t)c * D + q * 4);
    float* dst = out + (size_t)r * D + q * 4;
    unsafeAtomicAdd(dst + 0, v * xv.x);
    unsafeAtomicAdd(dst + 1, v * xv.y);
    unsafeAtomicAdd(dst + 2, v * xv.z);
    unsafeAtomicAdd(dst + 3, v * xv.w);
}

// Fused: feat_in[c] = concat(x[tu[c]], x[NU+ti[c]]) (+ cat_emb on layer 0)
//        feat_out[r] += v * feat_in[c]           (GX spmm)
//        upd[tu[r]] += feat_out_half0, upd[NU+ti[r]] += feat_out_half1
// applied per-nnz directly (linearity), so feat is never materialized.
// 32 threads per nnz: h in [0,32) covers 128 concat dims as float4 quads.
__global__ void gx_kernel(const int* __restrict__ rows, const int* __restrict__ cols,
                          const float* __restrict__ vals,
                          const int* __restrict__ tu, const int* __restrict__ ti,
                          const int* __restrict__ i2c, const float* __restrict__ cat_emb,
                          const float* __restrict__ x, float* __restrict__ upd,
                          int layer0) {
    int tid = blockIdx.x * blockDim.x + threadIdx.x;
    int j = tid >> 5;
    int h = tid & 31;
    if (j >= NNZ_GX) return;
    int r = rows[j], c = cols[j];
    float v = vals[j];
    int q = h & 15;
    int src, dst;
    if (h < 16) {
        src = tu[c];
        dst = tu[r];
    } else {
        src = NUM_USERS + ti[c];
        dst = NUM_USERS + ti[r];
    }
    float4 f = *(const float4*)(x + (size_t)src * D + q * 4);
    if (layer0) {
        int cat = i2c[ti[c]];
        const float4 cv = *(const float4*)(cat_emb + (size_t)cat * (2 * D) + h * 4);
        f.x += cv.x; f.y += cv.y; f.z += cv.z; f.w += cv.w;
    }
    float* dp = upd + (size_t)dst * D + q * 4;
    unsafeAtomicAdd(dp + 0, v * f.x);
    unsafeAtomicAdd(dp + 1, v * f.y);
    unsafeAtomicAdd(dp + 2, v * f.z);
    unsafeAtomicAdd(dp + 3, v * f.w);
}

// x_next = (upd * dinv + x) * 0.5 ; acc += x_next
__global__ void finalize_kernel(const float* __restrict__ xin, const float* __restrict__ upd,
                                const float* __restrict__ dinv, float* __restrict__ xout,
                                float* __restrict__ acc) {
    int i = blockIdx.x * blockDim.x + threadIdx.x;  // float4 quad index
    if (i >= N_NODES * D / 4) return;
    int node = i >> 4;
    float di = dinv[node];
    float4 u = ((const float4*)upd)[i];
    float4 xv = ((const float4*)xin)[i];
    float4 nx;
    nx.x = (u.x * di + xv.x) * 0.5f;
    nx.y = (u.y * di + xv.y) * 0.5f;
    nx.z = (u.z * di + xv.z) * 0.5f;
    nx.w = (u.w * di + xv.w) * 0.5f;
    ((float4*)xout)[i] = nx;
    float4 a = ((float4*)acc)[i];
    a.x += nx.x; a.y += nx.y; a.z += nx.z; a.w += nx.w;
    ((float4*)acc)[i] = a;
}

// gamma[b] = dot(acc[users[b]], acc[NU+items[b]]) / 9   (mean over 3 layers, both sides)
__global__ void gamma_kernel(const int* __restrict__ users, const int* __restrict__ items,
                             const float* __restrict__ acc, float* __restrict__ out) {
    int wave = (blockIdx.x * blockDim.x + threadIdx.x) >> 6;
    int lane = threadIdx.x & 63;
    if (wave >= BATCH) return;
    int u = users[wave], it = items[wave];
    float pu = acc[(size_t)u * D + lane];
    float pi = acc[(size_t)(NUM_USERS + it) * D + lane];
    float p = pu * pi;
#pragma unroll
    for (int off = 32; off > 0; off >>= 1) p += __shfl_down(p, off, 64);
    if (lane == 0) out[wave] = p * (1.0f / 9.0f);
}

extern "C" void kernel_launch(void* const* d_in, const int* in_sizes, int n_in,
                              void* d_out, int out_size, void* d_ws, size_t ws_size,
                              hipStream_t stream) {
    const float* user_emb = (const float*)d_in[0];
    const float* item_emb = (const float*)d_in[1];
    const float* cat_emb  = (const float*)d_in[2];
    const float* g_vals   = (const float*)d_in[3];
    const float* gx_vals  = (const float*)d_in[4];
    const int* g_rows  = (const int*)d_in[5];
    const int* g_cols  = (const int*)d_in[6];
    const int* gx_rows = (const int*)d_in[7];
    const int* gx_cols = (const int*)d_in[8];
    const int* train_users = (const int*)d_in[9];
    const int* train_items = (const int*)d_in[10];
    const int* i2c   = (const int*)d_in[11];
    const int* users = (const int*)d_in[12];
    const int* items = (const int*)d_in[13];
    float* out = (float*)d_out;

    char* ws = (char*)d_ws;
    const size_t NB = (size_t)N_NODES * D * sizeof(float);  // 25.6 MB
    float* bufA = (float*)(ws);             // current embeddings x
    float* bufB = (float*)(ws + NB);        // spmm_g output t
    float* upd  = (float*)(ws + 2 * NB);    // scatter accumulator
    float* acc  = (float*)(ws + 3 * NB);    // sum of layer outputs
    float* dinv = (float*)(ws + 4 * NB);    // degree -> 1/(deg+eps)
    // total workspace: 4*25.6 MB + 0.4 MB ~= 103 MB

    // init x = concat(user_emb, item_emb); acc = 0; degree = 0
    hipMemcpyAsync(bufA, user_emb, (size_t)NUM_USERS * D * sizeof(float),
                   hipMemcpyDeviceToDevice, stream);
    hipMemcpyAsync(bufA + (size_t)NUM_USERS * D, item_emb,
                   (size_t)NUM_ITEMS * D * sizeof(float),
                   hipMemcpyDeviceToDevice, stream);
    hipMemsetAsync(acc, 0, NB, stream);
    hipMemsetAsync(dinv, 0, (size_t)N_NODES * sizeof(float), stream);

    deg_kernel<<<(N_EDGES + 255) / 256, 256, 0, stream>>>(train_users, train_items, dinv);
    dinv_kernel<<<(N_NODES + 255) / 256, 256, 0, stream>>>(dinv);

    float* x = bufA;
    float* t = bufB;
    for (int layer = 0; layer < N_LAYERS; ++layer) {
        hipMemsetAsync(t, 0, NB, stream);
        spmm_g_kernel<<<(NNZ_G * 16 + 255) / 256, 256, 0, stream>>>(g_rows, g_cols, g_vals, x, t);
        hipMemsetAsync(upd, 0, NB, stream);
        int nthreads_gx_blocks = (int)(((long long)NNZ_GX * 32 + 255) / 256);
        gx_kernel<<<nthreads_gx_blocks, 256, 0, stream>>>(gx_rows, gx_cols, gx_vals,
                                                          train_users, train_items,
                                                          i2c, cat_emb, t, upd,
                                                          layer == 0 ? 1 : 0);
        finalize_kernel<<<(N_NODES * D / 4 + 255) / 256, 256, 0, stream>>>(t, upd, dinv, x, acc);
        // x (bufA) now holds this layer's output; t (bufB) reused next layer
    }

    gamma_kernel<<<(BATCH * 64 + 255) / 256, 256, 0, stream>>>(users, items, acc, out);
}

// Round 2
// 1733.866 us; speedup vs baseline: 7.4863x; 7.4863x over previous
//
#include <hip/hip_runtime.h>

#define NUM_USERS 50000
#define NUM_ITEMS 50000
#define NUM_CATS  500
#define D         64
#define N_LAYERS  3
#define N_EDGES   500000
#define NNZ_G     1000000
#define NNZ_GX    2000000
#define BATCH     8192
#define N_NODES   (NUM_USERS + NUM_ITEMS)

// ---------- degree ----------
__global__ void deg_kernel(const int* __restrict__ tu, const int* __restrict__ ti,
                           float* __restrict__ deg) {
    int e = blockIdx.x * blockDim.x + threadIdx.x;
    if (e >= N_EDGES) return;
    unsafeAtomicAdd(deg + tu[e], 1.0f);
    unsafeAtomicAdd(deg + NUM_USERS + ti[e], 1.0f);
}

__global__ void dinv_kernel(float* __restrict__ deg) {
    int n = blockIdx.x * blockDim.x + threadIdx.x;
    if (n < N_NODES) deg[n] = 1.0f / (deg[n] + 1e-9f);
}

// ---------- CSR build: histograms ----------
__global__ void hist_c_kernel(const int* __restrict__ gx_rows, const int* __restrict__ tu,
                              const int* __restrict__ ti, int* __restrict__ cnt) {
    int j = blockIdx.x * blockDim.x + threadIdx.x;
    if (j >= NNZ_GX) return;
    int r = gx_rows[j];
    atomicAdd(cnt + tu[r], 1);
    atomicAdd(cnt + NUM_USERS + ti[r], 1);
}

__global__ void hist_g_kernel(const int* __restrict__ g_rows, int* __restrict__ cnt) {
    int e = blockIdx.x * blockDim.x + threadIdx.x;
    if (e >= NNZ_G) return;
    atomicAdd(cnt + g_rows[e], 1);
}

// ---------- CSR build: exclusive scan (single workgroup, strip per thread) ----------
__global__ void scan_kernel(const int* __restrict__ cnt, int* __restrict__ row, int n) {
    __shared__ int sums[1024];
    const int T = 1024;
    int strip = (n + T - 1) / T;
    int t = threadIdx.x;
    int beg = t * strip;
    int end = beg + strip; if (end > n) end = n;
    int s = 0;
    for (int i = beg; i < end; ++i) s += cnt[i];
    sums[t] = s;
    __syncthreads();
    if (t == 0) {
        int run = 0;
        for (int i = 0; i < T; ++i) { int v = sums[i]; sums[i] = run; run += v; }
        row[n] = run;
    }
    __syncthreads();
    int run = sums[t];
    for (int i = beg; i < end; ++i) { row[i] = run; run += cnt[i]; }
}

// ---------- CSR build: scatter with atomic cursors ----------
// C graph: per gx nnz j, two edges:
//   user half: dst=tu[gx_rows[j]]       src=tu[gx_cols[j]]        cat=i2c[ti[gx_cols[j]]]*128
//   item half: dst=NU+ti[gx_rows[j]]    src=NU+ti[gx_cols[j]]     cat=...*128+64
__global__ void scatter_c_kernel(const int* __restrict__ gx_rows, const int* __restrict__ gx_cols,
                                 const float* __restrict__ gx_vals,
                                 const int* __restrict__ tu, const int* __restrict__ ti,
                                 const int* __restrict__ i2c,
                                 int* __restrict__ cur, int2* __restrict__ edges,
                                 int* __restrict__ catoff) {
    int j = blockIdx.x * blockDim.x + threadIdx.x;
    if (j >= NNZ_GX) return;
    int r = gx_rows[j], c = gx_cols[j];
    int vbits = __float_as_int(gx_vals[j]);
    int tic = ti[c];
    int cat = i2c[tic] * (2 * D);
    int pu = atomicAdd(cur + tu[r], 1);
    edges[pu] = make_int2(tu[c] * D, vbits);
    catoff[pu] = cat;
    int pi = atomicAdd(cur + NUM_USERS + ti[r], 1);
    edges[pi] = make_int2((NUM_USERS + tic) * D, vbits);
    catoff[pi] = cat + D;
}

__global__ void scatter_g_kernel(const int* __restrict__ g_rows, const int* __restrict__ g_cols,
                                 const float* __restrict__ g_vals,
                                 int* __restrict__ cur, int2* __restrict__ edges) {
    int e = blockIdx.x * blockDim.x + threadIdx.x;
    if (e >= NNZ_G) return;
    int p = atomicAdd(cur + g_rows[e], 1);
    edges[p] = make_int2(g_cols[e] * D, __float_as_int(g_vals[e]));
}

// ---------- pull SpMM: one wave per destination node, lane = dim ----------
__global__ void pull_kernel(const int* __restrict__ row, const int2* __restrict__ edges,
                            const int* __restrict__ catoff, const float* __restrict__ catbase,
                            const float* __restrict__ x, float* __restrict__ out) {
    int wave = (blockIdx.x * blockDim.x + threadIdx.x) >> 6;
    int lane = threadIdx.x & 63;
    if (wave >= N_NODES) return;
    int beg = row[wave], end = row[wave + 1];
    float acc = 0.f;
    if (catoff) {
        #pragma unroll 4
        for (int i = beg; i < end; ++i) {
            int2 e = edges[i];
            float v = __int_as_float(e.y);
            acc += v * (x[e.x + lane] + catbase[catoff[i] + lane]);
        }
    } else {
        #pragma unroll 4
        for (int i = beg; i < end; ++i) {
            int2 e = edges[i];
            acc += __int_as_float(e.y) * x[e.x + lane];
        }
    }
    out[(size_t)wave * D + lane] = acc;
}

// ---------- x_next = (upd*dinv + t)*0.5 ; acc += x_next ----------
__global__ void finalize_kernel(const float* __restrict__ xin, const float* __restrict__ upd,
                                const float* __restrict__ dinv, float* __restrict__ xout,
                                float* __restrict__ acc) {
    int i = blockIdx.x * blockDim.x + threadIdx.x;
    if (i >= N_NODES * D / 4) return;
    int node = i >> 4;
    float di = dinv[node];
    float4 u = ((const float4*)upd)[i];
    float4 xv = ((const float4*)xin)[i];
    float4 nx;
    nx.x = (u.x * di + xv.x) * 0.5f;
    nx.y = (u.y * di + xv.y) * 0.5f;
    nx.z = (u.z * di + xv.z) * 0.5f;
    nx.w = (u.w * di + xv.w) * 0.5f;
    ((float4*)xout)[i] = nx;
    float4 a = ((float4*)acc)[i];
    a.x += nx.x; a.y += nx.y; a.z += nx.z; a.w += nx.w;
    ((float4*)acc)[i] = a;
}

// ---------- gamma ----------
__global__ void gamma_kernel(const int* __restrict__ users, const int* __restrict__ items,
                             const float* __restrict__ acc, float* __restrict__ out) {
    int wave = (blockIdx.x * blockDim.x + threadIdx.x) >> 6;
    int lane = threadIdx.x & 63;
    if (wave >= BATCH) return;
    int u = users[wave], it = items[wave];
    float p = acc[(size_t)u * D + lane] * acc[(size_t)(NUM_USERS + it) * D + lane];
#pragma unroll
    for (int off = 32; off > 0; off >>= 1) p += __shfl_down(p, off, 64);
    if (lane == 0) out[wave] = p * (1.0f / 9.0f);
}

extern "C" void kernel_launch(void* const* d_in, const int* in_sizes, int n_in,
                              void* d_out, int out_size, void* d_ws, size_t ws_size,
                              hipStream_t stream) {
    const float* user_emb = (const float*)d_in[0];
    const float* item_emb = (const float*)d_in[1];
    const float* cat_emb  = (const float*)d_in[2];
    const float* g_vals   = (const float*)d_in[3];
    const float* gx_vals  = (const float*)d_in[4];
    const int* g_rows  = (const int*)d_in[5];
    const int* g_cols  = (const int*)d_in[6];
    const int* gx_rows = (const int*)d_in[7];
    const int* gx_cols = (const int*)d_in[8];
    const int* train_users = (const int*)d_in[9];
    const int* train_items = (const int*)d_in[10];
    const int* i2c   = (const int*)d_in[11];
    const int* users = (const int*)d_in[12];
    const int* items = (const int*)d_in[13];
    float* out = (float*)d_out;

    char* ws = (char*)d_ws;
    size_t off = 0;
    auto alloc = [&](size_t bytes) -> void* {
        void* p = ws + off;
        off += (bytes + 255) & ~(size_t)255;
        return p;
    };
    const size_t NB = (size_t)N_NODES * D * sizeof(float);  // 25.6 MB
    float* x    = (float*)alloc(NB);
    float* t    = (float*)alloc(NB);
    float* upd  = (float*)alloc(NB);
    float* acc  = (float*)alloc(NB);
    float* dinv = (float*)alloc((size_t)N_NODES * sizeof(float));
    int*  rowC  = (int*)alloc((size_t)(N_NODES + 1) * sizeof(int));
    int*  curC  = (int*)alloc((size_t)N_NODES * sizeof(int));
    int*  rowG  = (int*)alloc((size_t)(N_NODES + 1) * sizeof(int));
    int*  curG  = (int*)alloc((size_t)N_NODES * sizeof(int));
    int2* edgeC = (int2*)alloc((size_t)2 * NNZ_GX * sizeof(int2));  // 32 MB
    int*  catA  = (int*)alloc((size_t)2 * NNZ_GX * sizeof(int));    // 16 MB
    int2* edgeG = (int2*)alloc((size_t)NNZ_G * sizeof(int2));       // 8 MB
    // total ~ 160 MB

    // init
    hipMemcpyAsync(x, user_emb, (size_t)NUM_USERS * D * sizeof(float),
                   hipMemcpyDeviceToDevice, stream);
    hipMemcpyAsync(x + (size_t)NUM_USERS * D, item_emb,
                   (size_t)NUM_ITEMS * D * sizeof(float),
                   hipMemcpyDeviceToDevice, stream);
    hipMemsetAsync(acc, 0, NB, stream);
    hipMemsetAsync(dinv, 0, (size_t)N_NODES * sizeof(float), stream);
    hipMemsetAsync(curC, 0, (size_t)N_NODES * sizeof(int), stream);
    hipMemsetAsync(curG, 0, (size_t)N_NODES * sizeof(int), stream);

    deg_kernel<<<(N_EDGES + 255) / 256, 256, 0, stream>>>(train_users, train_items, dinv);
    dinv_kernel<<<(N_NODES + 255) / 256, 256, 0, stream>>>(dinv);

    // CSR build (curC/curG double as histogram buffers)
    hist_c_kernel<<<(NNZ_GX + 255) / 256, 256, 0, stream>>>(gx_rows, train_users, train_items, curC);
    hist_g_kernel<<<(NNZ_G + 255) / 256, 256, 0, stream>>>(g_rows, curG);
    scan_kernel<<<1, 1024, 0, stream>>>(curC, rowC, N_NODES);
    scan_kernel<<<1, 1024, 0, stream>>>(curG, rowG, N_NODES);
    hipMemcpyAsync(curC, rowC, (size_t)N_NODES * sizeof(int), hipMemcpyDeviceToDevice, stream);
    hipMemcpyAsync(curG, rowG, (size_t)N_NODES * sizeof(int), hipMemcpyDeviceToDevice, stream);
    scatter_c_kernel<<<(NNZ_GX + 255) / 256, 256, 0, stream>>>(gx_rows, gx_cols, gx_vals,
                                                               train_users, train_items, i2c,
                                                               curC, edgeC, catA);
    scatter_g_kernel<<<(NNZ_G + 255) / 256, 256, 0, stream>>>(g_rows, g_cols, g_vals, curG, edgeG);

    const int pull_grid = (N_NODES * 64 + 255) / 256;
    for (int layer = 0; layer < N_LAYERS; ++layer) {
        // t = G * x
        pull_kernel<<<pull_grid, 256, 0, stream>>>(rowG, edgeG, nullptr, nullptr, x, t);
        // upd = C * t (+ cat side-input on layer 0)
        pull_kernel<<<pull_grid, 256, 0, stream>>>(rowC, edgeC,
                                                   layer == 0 ? catA : nullptr, cat_emb, t, upd);
        // x = (upd*dinv + t)*0.5 ; acc += x
        finalize_kernel<<<(N_NODES * D / 4 + 255) / 256, 256, 0, stream>>>(t, upd, dinv, x, acc);
    }

    gamma_kernel<<<(BATCH * 64 + 255) / 256, 256, 0, stream>>>(users, items, acc, out);
}

// Round 3
// 1520.115 us; speedup vs baseline: 8.5390x; 1.1406x over previous
//
#include <hip/hip_runtime.h>

#define NUM_USERS 50000
#define NUM_ITEMS 50000
#define NUM_CATS  500
#define D         64
#define N_LAYERS  3
#define N_EDGES   500000
#define NNZ_G     1000000
#define NNZ_GX    2000000
#define BATCH     8192
#define N_NODES   (NUM_USERS + NUM_ITEMS)

// ---------- degree ----------
__global__ void deg_kernel(const int* __restrict__ tu, const int* __restrict__ ti,
                           float* __restrict__ deg) {
    int e = blockIdx.x * blockDim.x + threadIdx.x;
    if (e >= N_EDGES) return;
    unsafeAtomicAdd(deg + tu[e], 1.0f);
    unsafeAtomicAdd(deg + NUM_USERS + ti[e], 1.0f);
}

__global__ void dinv_kernel(float* __restrict__ deg) {
    int n = blockIdx.x * blockDim.x + threadIdx.x;
    if (n < N_NODES) deg[n] = 1.0f / (deg[n] + 1e-9f);
}

// ---------- CSR build: histograms ----------
__global__ void hist_c_kernel(const int* __restrict__ gx_rows, const int* __restrict__ tu,
                              const int* __restrict__ ti, int* __restrict__ cnt) {
    int j = blockIdx.x * blockDim.x + threadIdx.x;
    if (j >= NNZ_GX) return;
    int r = gx_rows[j];
    atomicAdd(cnt + tu[r], 1);
    atomicAdd(cnt + NUM_USERS + ti[r], 1);
}

__global__ void hist_g_kernel(const int* __restrict__ g_rows, int* __restrict__ cnt) {
    int e = blockIdx.x * blockDim.x + threadIdx.x;
    if (e >= NNZ_G) return;
    atomicAdd(cnt + g_rows[e], 1);
}

// ---------- CSR build: exclusive scan (single workgroup) ----------
__global__ void scan_kernel(const int* __restrict__ cnt, int* __restrict__ row, int n) {
    __shared__ int sums[1024];
    const int T = 1024;
    int strip = (n + T - 1) / T;
    int t = threadIdx.x;
    int beg = t * strip;
    int end = beg + strip; if (end > n) end = n;
    int s = 0;
    for (int i = beg; i < end; ++i) s += cnt[i];
    sums[t] = s;
    __syncthreads();
    if (t == 0) {
        int run = 0;
        for (int i = 0; i < T; ++i) { int v = sums[i]; sums[i] = run; run += v; }
        row[n] = run;
    }
    __syncthreads();
    int run = sums[t];
    for (int i = beg; i < end; ++i) { row[i] = run; run += cnt[i]; }
}

// ---------- CSR build: scatter with atomic cursors ----------
// C edge payload: e.x = (src_node << 10) | (cat << 1) | half   (src<2^17, cat<512)
//                 e.y = value bits
__global__ void scatter_c_kernel(const int* __restrict__ gx_rows, const int* __restrict__ gx_cols,
                                 const float* __restrict__ gx_vals,
                                 const int* __restrict__ tu, const int* __restrict__ ti,
                                 const int* __restrict__ i2c,
                                 int* __restrict__ cur, int2* __restrict__ edges) {
    int j = blockIdx.x * blockDim.x + threadIdx.x;
    if (j >= NNZ_GX) return;
    int r = gx_rows[j], c = gx_cols[j];
    int vbits = __float_as_int(gx_vals[j]);
    int tic = ti[c];
    int cat2 = i2c[tic] << 1;
    int pu = atomicAdd(cur + tu[r], 1);
    edges[pu] = make_int2((tu[c] << 10) | cat2, vbits);
    int pi = atomicAdd(cur + NUM_USERS + ti[r], 1);
    edges[pi] = make_int2(((NUM_USERS + tic) << 10) | cat2 | 1, vbits);
}

// G edge payload: e.x = src*D directly
__global__ void scatter_g_kernel(const int* __restrict__ g_rows, const int* __restrict__ g_cols,
                                 const float* __restrict__ g_vals,
                                 int* __restrict__ cur, int2* __restrict__ edges) {
    int e = blockIdx.x * blockDim.x + threadIdx.x;
    if (e >= NNZ_G) return;
    int p = atomicAdd(cur + g_rows[e], 1);
    edges[p] = make_int2(g_cols[e] * D, __float_as_int(g_vals[e]));
}

// ---------- pull SpMM (G): one wave per dst node, 16 lanes/edge, float4 ----------
__global__ void pull_g_kernel(const int* __restrict__ row, const int2* __restrict__ edges,
                              const float* __restrict__ x, float* __restrict__ out) {
    int wave = (blockIdx.x * blockDim.x + threadIdx.x) >> 6;
    int lane = threadIdx.x & 63;
    if (wave >= N_NODES) return;
    int eg = lane >> 4;      // edge group 0..3
    int q  = lane & 15;      // float4 quad within row
    int beg = row[wave], end = row[wave + 1];
    float4 acc = make_float4(0.f, 0.f, 0.f, 0.f);
    #pragma unroll 2
    for (int i = beg + eg; i < end; i += 4) {
        int2 e = edges[i];
        float v = __int_as_float(e.y);
        float4 xv = *(const float4*)(x + e.x + q * 4);
        acc.x += v * xv.x; acc.y += v * xv.y; acc.z += v * xv.z; acc.w += v * xv.w;
    }
    // reduce across the 4 edge groups
    acc.x += __shfl_xor(acc.x, 16, 64); acc.y += __shfl_xor(acc.y, 16, 64);
    acc.z += __shfl_xor(acc.z, 16, 64); acc.w += __shfl_xor(acc.w, 16, 64);
    acc.x += __shfl_xor(acc.x, 32, 64); acc.y += __shfl_xor(acc.y, 32, 64);
    acc.z += __shfl_xor(acc.z, 32, 64); acc.w += __shfl_xor(acc.w, 32, 64);
    if (lane < 16) *(float4*)(out + (size_t)wave * D + q * 4) = acc;
}

// ---------- pull SpMM (C): packed payload, optional cat side-input ----------
template <int LAYER0>
__global__ void pull_c_kernel(const int* __restrict__ row, const int2* __restrict__ edges,
                              const float* __restrict__ catbase,
                              const float* __restrict__ x, float* __restrict__ out) {
    int wave = (blockIdx.x * blockDim.x + threadIdx.x) >> 6;
    int lane = threadIdx.x & 63;
    if (wave >= N_NODES) return;
    int eg = lane >> 4;
    int q  = lane & 15;
    int beg = row[wave], end = row[wave + 1];
    float4 acc = make_float4(0.f, 0.f, 0.f, 0.f);
    #pragma unroll 2
    for (int i = beg + eg; i < end; i += 4) {
        int2 e = edges[i];
        float v = __int_as_float(e.y);
        int src = e.x >> 10;
        float4 xv = *(const float4*)(x + src * D + q * 4);
        if (LAYER0) {
            int code = e.x & 1023;  // (cat<<1)|half
            int catoff = (code >> 1) * (2 * D) + ((code & 1) << 6);
            const float4 cv = *(const float4*)(catbase + catoff + q * 4);
            xv.x += cv.x; xv.y += cv.y; xv.z += cv.z; xv.w += cv.w;
        }
        acc.x += v * xv.x; acc.y += v * xv.y; acc.z += v * xv.z; acc.w += v * xv.w;
    }
    acc.x += __shfl_xor(acc.x, 16, 64); acc.y += __shfl_xor(acc.y, 16, 64);
    acc.z += __shfl_xor(acc.z, 16, 64); acc.w += __shfl_xor(acc.w, 16, 64);
    acc.x += __shfl_xor(acc.x, 32, 64); acc.y += __shfl_xor(acc.y, 32, 64);
    acc.z += __shfl_xor(acc.z, 32, 64); acc.w += __shfl_xor(acc.w, 32, 64);
    if (lane < 16) *(float4*)(out + (size_t)wave * D + q * 4) = acc;
}

// ---------- x_next = (upd*dinv + t)*0.5 ; acc += x_next ----------
__global__ void finalize_kernel(const float* __restrict__ xin, const float* __restrict__ upd,
                                const float* __restrict__ dinv, float* __restrict__ xout,
                                float* __restrict__ acc) {
    int i = blockIdx.x * blockDim.x + threadIdx.x;
    if (i >= N_NODES * D / 4) return;
    int node = i >> 4;
    float di = dinv[node];
    float4 u = ((const float4*)upd)[i];
    float4 xv = ((const float4*)xin)[i];
    float4 nx;
    nx.x = (u.x * di + xv.x) * 0.5f;
    nx.y = (u.y * di + xv.y) * 0.5f;
    nx.z = (u.z * di + xv.z) * 0.5f;
    nx.w = (u.w * di + xv.w) * 0.5f;
    ((float4*)xout)[i] = nx;
    float4 a = ((float4*)acc)[i];
    a.x += nx.x; a.y += nx.y; a.z += nx.z; a.w += nx.w;
    ((float4*)acc)[i] = a;
}

// ---------- gamma ----------
__global__ void gamma_kernel(const int* __restrict__ users, const int* __restrict__ items,
                             const float* __restrict__ acc, float* __restrict__ out) {
    int wave = (blockIdx.x * blockDim.x + threadIdx.x) >> 6;
    int lane = threadIdx.x & 63;
    if (wave >= BATCH) return;
    int u = users[wave], it = items[wave];
    float p = acc[(size_t)u * D + lane] * acc[(size_t)(NUM_USERS + it) * D + lane];
#pragma unroll
    for (int off = 32; off > 0; off >>= 1) p += __shfl_down(p, off, 64);
    if (lane == 0) out[wave] = p * (1.0f / 9.0f);
}

extern "C" void kernel_launch(void* const* d_in, const int* in_sizes, int n_in,
                              void* d_out, int out_size, void* d_ws, size_t ws_size,
                              hipStream_t stream) {
    const float* user_emb = (const float*)d_in[0];
    const float* item_emb = (const float*)d_in[1];
    const float* cat_emb  = (const float*)d_in[2];
    const float* g_vals   = (const float*)d_in[3];
    const float* gx_vals  = (const float*)d_in[4];
    const int* g_rows  = (const int*)d_in[5];
    const int* g_cols  = (const int*)d_in[6];
    const int* gx_rows = (const int*)d_in[7];
    const int* gx_cols = (const int*)d_in[8];
    const int* train_users = (const int*)d_in[9];
    const int* train_items = (const int*)d_in[10];
    const int* i2c   = (const int*)d_in[11];
    const int* users = (const int*)d_in[12];
    const int* items = (const int*)d_in[13];
    float* out = (float*)d_out;

    char* ws = (char*)d_ws;
    size_t off = 0;
    auto alloc = [&](size_t bytes) -> void* {
        void* p = ws + off;
        off += (bytes + 255) & ~(size_t)255;
        return p;
    };
    const size_t NB = (size_t)N_NODES * D * sizeof(float);  // 25.6 MB
    float* x    = (float*)alloc(NB);
    float* t    = (float*)alloc(NB);
    float* upd  = (float*)alloc(NB);
    float* acc  = (float*)alloc(NB);
    float* dinv = (float*)alloc((size_t)N_NODES * sizeof(float));
    int*  rowC  = (int*)alloc((size_t)(N_NODES + 1) * sizeof(int));
    int*  curC  = (int*)alloc((size_t)N_NODES * sizeof(int));
    int*  rowG  = (int*)alloc((size_t)(N_NODES + 1) * sizeof(int));
    int*  curG  = (int*)alloc((size_t)N_NODES * sizeof(int));
    int2* edgeC = (int2*)alloc((size_t)2 * NNZ_GX * sizeof(int2));  // 32 MB
    int2* edgeG = (int2*)alloc((size_t)NNZ_G * sizeof(int2));       // 8 MB

    // init
    hipMemcpyAsync(x, user_emb, (size_t)NUM_USERS * D * sizeof(float),
                   hipMemcpyDeviceToDevice, stream);
    hipMemcpyAsync(x + (size_t)NUM_USERS * D, item_emb,
                   (size_t)NUM_ITEMS * D * sizeof(float),
                   hipMemcpyDeviceToDevice, stream);
    hipMemsetAsync(acc, 0, NB, stream);
    hipMemsetAsync(dinv, 0, (size_t)N_NODES * sizeof(float), stream);
    hipMemsetAsync(curC, 0, (size_t)N_NODES * sizeof(int), stream);
    hipMemsetAsync(curG, 0, (size_t)N_NODES * sizeof(int), stream);

    deg_kernel<<<(N_EDGES + 255) / 256, 256, 0, stream>>>(train_users, train_items, dinv);
    dinv_kernel<<<(N_NODES + 255) / 256, 256, 0, stream>>>(dinv);

    hist_c_kernel<<<(NNZ_GX + 255) / 256, 256, 0, stream>>>(gx_rows, train_users, train_items, curC);
    hist_g_kernel<<<(NNZ_G + 255) / 256, 256, 0, stream>>>(g_rows, curG);
    scan_kernel<<<1, 1024, 0, stream>>>(curC, rowC, N_NODES);
    scan_kernel<<<1, 1024, 0, stream>>>(curG, rowG, N_NODES);
    hipMemcpyAsync(curC, rowC, (size_t)N_NODES * sizeof(int), hipMemcpyDeviceToDevice, stream);
    hipMemcpyAsync(curG, rowG, (size_t)N_NODES * sizeof(int), hipMemcpyDeviceToDevice, stream);
    scatter_c_kernel<<<(NNZ_GX + 255) / 256, 256, 0, stream>>>(gx_rows, gx_cols, gx_vals,
                                                               train_users, train_items, i2c,
                                                               curC, edgeC);
    scatter_g_kernel<<<(NNZ_G + 255) / 256, 256, 0, stream>>>(g_rows, g_cols, g_vals, curG, edgeG);

    const int pull_grid = (N_NODES * 64 + 255) / 256;
    for (int layer = 0; layer < N_LAYERS; ++layer) {
        pull_g_kernel<<<pull_grid, 256, 0, stream>>>(rowG, edgeG, x, t);
        if (layer == 0)
            pull_c_kernel<1><<<pull_grid, 256, 0, stream>>>(rowC, edgeC, cat_emb, t, upd);
        else
            pull_c_kernel<0><<<pull_grid, 256, 0, stream>>>(rowC, edgeC, cat_emb, t, upd);
        finalize_kernel<<<(N_NODES * D / 4 + 255) / 256, 256, 0, stream>>>(t, upd, dinv, x, acc);
    }

    gamma_kernel<<<(BATCH * 64 + 255) / 256, 256, 0, stream>>>(users, items, acc, out);
}

// Round 4
// 1018.443 us; speedup vs baseline: 12.7453x; 1.4926x over previous
//
#include <hip/hip_runtime.h>

#define NUM_USERS 50000
#define NUM_ITEMS 50000
#define NUM_CATS  500
#define D         64
#define N_LAYERS  3
#define N_EDGES   500000
#define NNZ_G     1000000
#define NNZ_GX    2000000
#define BATCH     8192
#define N_NODES   (NUM_USERS + NUM_ITEMS)

#define BKT_SHIFT 4
#define BKT_W     16
#define NBKT      (N_NODES / BKT_W)   // 6250 (100000 = 6250*16 exactly)

// ---------- degree ----------
__global__ void deg_kernel(const int* __restrict__ tu, const int* __restrict__ ti,
                           float* __restrict__ deg) {
    int e = blockIdx.x * blockDim.x + threadIdx.x;
    if (e >= N_EDGES) return;
    unsafeAtomicAdd(deg + tu[e], 1.0f);
    unsafeAtomicAdd(deg + NUM_USERS + ti[e], 1.0f);
}

__global__ void dinv_kernel(float* __restrict__ deg) {
    int n = blockIdx.x * blockDim.x + threadIdx.x;
    if (n < N_NODES) deg[n] = 1.0f / (deg[n] + 1e-9f);
}

// ---------- bucket histograms (C and G), LDS-buffered ----------
__global__ void hist_both_kernel(const int* __restrict__ gx_rows,
                                 const int* __restrict__ tu, const int* __restrict__ ti,
                                 const int* __restrict__ g_rows,
                                 int* __restrict__ cntC, int* __restrict__ cntG) {
    __shared__ int hC[NBKT];
    __shared__ int hG[NBKT];
    for (int i = threadIdx.x; i < NBKT; i += blockDim.x) { hC[i] = 0; hG[i] = 0; }
    __syncthreads();
    int stride = gridDim.x * blockDim.x;
    int t0 = blockIdx.x * blockDim.x + threadIdx.x;
    for (int j = t0; j < NNZ_GX; j += stride) {
        int r = gx_rows[j];
        atomicAdd(hC + (tu[r] >> BKT_SHIFT), 1);
        atomicAdd(hC + ((NUM_USERS + ti[r]) >> BKT_SHIFT), 1);
    }
    for (int e = t0; e < NNZ_G; e += stride) {
        atomicAdd(hG + (g_rows[e] >> BKT_SHIFT), 1);
    }
    __syncthreads();
    for (int i = threadIdx.x; i < NBKT; i += blockDim.x) {
        int c = hC[i]; if (c) atomicAdd(cntC + i, c);
        int g = hG[i]; if (g) atomicAdd(cntG + i, g);
    }
}

// ---------- scan over buckets: block 0 = C, block 1 = G ----------
// writes off[0..NBKT], cur[0..NBKT-1] (=off copy), row[N_NODES] sentinel
__global__ void scan2_kernel(const int* __restrict__ cntC, int* __restrict__ offC,
                             int* __restrict__ curC, int* __restrict__ rowC,
                             const int* __restrict__ cntG, int* __restrict__ offG,
                             int* __restrict__ curG, int* __restrict__ rowG) {
    const int* cnt = blockIdx.x ? cntG : cntC;
    int* off = blockIdx.x ? offG : offC;
    int* cur = blockIdx.x ? curG : curC;
    int* row = blockIdx.x ? rowG : rowC;
    __shared__ int sums[1024];
    const int T = 1024;
    const int strip = (NBKT + T - 1) / T;
    int t = threadIdx.x;
    int beg = t * strip;
    int end = beg + strip; if (end > NBKT) end = NBKT;
    int s = 0;
    for (int i = beg; i < end; ++i) s += cnt[i];
    sums[t] = s;
    __syncthreads();
    if (t == 0) {
        int run = 0;
        for (int i = 0; i < T; ++i) { int v = sums[i]; sums[i] = run; run += v; }
        off[NBKT] = run;
        row[N_NODES] = run;
    }
    __syncthreads();
    int run = sums[t];
    for (int i = beg; i < end; ++i) { off[i] = run; cur[i] = run; run += cnt[i]; }
}

// ---------- append into buckets (temporally-coalesced writes) ----------
// C payload: e.x = (dst_local<<27) | (src<<10) | (cat<<1) | half
__global__ void append_c_kernel(const int* __restrict__ gx_rows, const int* __restrict__ gx_cols,
                                const float* __restrict__ gx_vals,
                                const int* __restrict__ tu, const int* __restrict__ ti,
                                const int* __restrict__ i2c,
                                int* __restrict__ cur, int2* __restrict__ edges) {
    int j = blockIdx.x * blockDim.x + threadIdx.x;
    if (j >= NNZ_GX) return;
    int r = gx_rows[j], c = gx_cols[j];
    int vbits = __float_as_int(gx_vals[j]);
    int tic = ti[c];
    int cat2 = i2c[tic] << 1;
    int du = tu[r];
    int pu = atomicAdd(cur + (du >> BKT_SHIFT), 1);
    edges[pu] = make_int2(((du & (BKT_W - 1)) << 27) | (tu[c] << 10) | cat2, vbits);
    int dv = NUM_USERS + ti[r];
    int pi = atomicAdd(cur + (dv >> BKT_SHIFT), 1);
    edges[pi] = make_int2(((dv & (BKT_W - 1)) << 27) | ((NUM_USERS + tic) << 10) | cat2 | 1, vbits);
}

// G payload: e.x = (dst_local<<17) | src
__global__ void append_g_kernel(const int* __restrict__ g_rows, const int* __restrict__ g_cols,
                                const float* __restrict__ g_vals,
                                int* __restrict__ cur, int2* __restrict__ edges) {
    int e = blockIdx.x * blockDim.x + threadIdx.x;
    if (e >= NNZ_G) return;
    int dst = g_rows[e];
    int p = atomicAdd(cur + (dst >> BKT_SHIFT), 1);
    edges[p] = make_int2(((dst & (BKT_W - 1)) << 17) | g_cols[e], __float_as_int(g_vals[e]));
}

// ---------- per-bucket counting sort (no LDS staging of edges; two reads) ----------
// emits per-node CSR row starts + sorted edge arrays
__global__ void sort_c_kernel(const int* __restrict__ off, const int2* __restrict__ raw,
                              int2* __restrict__ sorted, int* __restrict__ rowC) {
    int b = blockIdx.x;
    int base = off[b], end = off[b + 1];
    __shared__ int hist[BKT_W], cur[BKT_W], scn[BKT_W];
    if (threadIdx.x < BKT_W) hist[threadIdx.x] = 0;
    __syncthreads();
    for (int i = base + threadIdx.x; i < end; i += blockDim.x)
        atomicAdd(hist + ((raw[i].x >> 27) & 15), 1);
    __syncthreads();
    if (threadIdx.x == 0) {
        int run = 0;
        for (int k = 0; k < BKT_W; ++k) { scn[k] = run; cur[k] = run; run += hist[k]; }
    }
    __syncthreads();
    if (threadIdx.x < BKT_W) rowC[b * BKT_W + threadIdx.x] = base + scn[threadIdx.x];
    for (int i = base + threadIdx.x; i < end; i += blockDim.x) {
        int2 e = raw[i];
        int dl = (e.x >> 27) & 15;
        int p = atomicAdd(cur + dl, 1);
        sorted[base + p] = make_int2(e.x & 0x07FFFFFF, e.y);
    }
}

__global__ void sort_g_kernel(const int* __restrict__ off, const int2* __restrict__ raw,
                              int2* __restrict__ sorted, int* __restrict__ rowG) {
    int b = blockIdx.x;
    int base = off[b], end = off[b + 1];
    __shared__ int hist[BKT_W], cur[BKT_W], scn[BKT_W];
    if (threadIdx.x < BKT_W) hist[threadIdx.x] = 0;
    __syncthreads();
    for (int i = base + threadIdx.x; i < end; i += blockDim.x)
        atomicAdd(hist + ((raw[i].x >> 17) & 15), 1);
    __syncthreads();
    if (threadIdx.x == 0) {
        int run = 0;
        for (int k = 0; k < BKT_W; ++k) { scn[k] = run; cur[k] = run; run += hist[k]; }
    }
    __syncthreads();
    if (threadIdx.x < BKT_W) rowG[b * BKT_W + threadIdx.x] = base + scn[threadIdx.x];
    for (int i = base + threadIdx.x; i < end; i += blockDim.x) {
        int2 e = raw[i];
        int dl = (e.x >> 17) & 15;
        int p = atomicAdd(cur + dl, 1);
        sorted[base + p] = make_int2((e.x & 0x1FFFF) << 6, e.y);  // src*64
    }
}

// ---------- pull SpMM (G): one wave per dst node, 16 lanes/edge, float4 ----------
__global__ void pull_g_kernel(const int* __restrict__ row, const int2* __restrict__ edges,
                              const float* __restrict__ x, float* __restrict__ out) {
    int wave = (blockIdx.x * blockDim.x + threadIdx.x) >> 6;
    int lane = threadIdx.x & 63;
    if (wave >= N_NODES) return;
    int eg = lane >> 4;
    int q  = lane & 15;
    int beg = row[wave], end = row[wave + 1];
    float4 acc = make_float4(0.f, 0.f, 0.f, 0.f);
    #pragma unroll 2
    for (int i = beg + eg; i < end; i += 4) {
        int2 e = edges[i];
        float v = __int_as_float(e.y);
        float4 xv = *(const float4*)(x + e.x + q * 4);
        acc.x += v * xv.x; acc.y += v * xv.y; acc.z += v * xv.z; acc.w += v * xv.w;
    }
    acc.x += __shfl_xor(acc.x, 16, 64); acc.y += __shfl_xor(acc.y, 16, 64);
    acc.z += __shfl_xor(acc.z, 16, 64); acc.w += __shfl_xor(acc.w, 16, 64);
    acc.x += __shfl_xor(acc.x, 32, 64); acc.y += __shfl_xor(acc.y, 32, 64);
    acc.z += __shfl_xor(acc.z, 32, 64); acc.w += __shfl_xor(acc.w, 32, 64);
    if (lane < 16) *(float4*)(out + (size_t)wave * D + q * 4) = acc;
}

// ---------- pull SpMM (C) fused with finalize ----------
// upd_row computed in regs; then x = (upd*dinv + t)*0.5 ; accb += x
template <int LAYER0>
__global__ void pull_c_fused(const int* __restrict__ row, const int2* __restrict__ edges,
                             const float* __restrict__ catbase,
                             const float* __restrict__ t, const float* __restrict__ dinv,
                             float* __restrict__ x, float* __restrict__ accb) {
    int wave = (blockIdx.x * blockDim.x + threadIdx.x) >> 6;
    int lane = threadIdx.x & 63;
    if (wave >= N_NODES) return;
    int eg = lane >> 4;
    int q  = lane & 15;
    int beg = row[wave], end = row[wave + 1];
    float4 acc = make_float4(0.f, 0.f, 0.f, 0.f);
    #pragma unroll 2
    for (int i = beg + eg; i < end; i += 4) {
        int2 e = edges[i];
        float v = __int_as_float(e.y);
        int src = e.x >> 10;
        float4 xv = *(const float4*)(t + src * D + q * 4);
        if (LAYER0) {
            int code = e.x & 1023;  // (cat<<1)|half
            int catoff = (code >> 1) * (2 * D) + ((code & 1) << 6);
            const float4 cv = *(const float4*)(catbase + catoff + q * 4);
            xv.x += cv.x; xv.y += cv.y; xv.z += cv.z; xv.w += cv.w;
        }
        acc.x += v * xv.x; acc.y += v * xv.y; acc.z += v * xv.z; acc.w += v * xv.w;
    }
    acc.x += __shfl_xor(acc.x, 16, 64); acc.y += __shfl_xor(acc.y, 16, 64);
    acc.z += __shfl_xor(acc.z, 16, 64); acc.w += __shfl_xor(acc.w, 16, 64);
    acc.x += __shfl_xor(acc.x, 32, 64); acc.y += __shfl_xor(acc.y, 32, 64);
    acc.z += __shfl_xor(acc.z, 32, 64); acc.w += __shfl_xor(acc.w, 32, 64);
    if (lane < 16) {
        float di = dinv[wave];
        size_t o = (size_t)wave * D + q * 4;
        float4 tv = *(const float4*)(t + o);
        float4 nx;
        nx.x = (acc.x * di + tv.x) * 0.5f;
        nx.y = (acc.y * di + tv.y) * 0.5f;
        nx.z = (acc.z * di + tv.z) * 0.5f;
        nx.w = (acc.w * di + tv.w) * 0.5f;
        *(float4*)(x + o) = nx;
        float4 av = *(const float4*)(accb + o);
        av.x += nx.x; av.y += nx.y; av.z += nx.z; av.w += nx.w;
        *(float4*)(accb + o) = av;
    }
}

// ---------- gamma ----------
__global__ void gamma_kernel(const int* __restrict__ users, const int* __restrict__ items,
                             const float* __restrict__ acc, float* __restrict__ out) {
    int wave = (blockIdx.x * blockDim.x + threadIdx.x) >> 6;
    int lane = threadIdx.x & 63;
    if (wave >= BATCH) return;
    int u = users[wave], it = items[wave];
    float p = acc[(size_t)u * D + lane] * acc[(size_t)(NUM_USERS + it) * D + lane];
#pragma unroll
    for (int off = 32; off > 0; off >>= 1) p += __shfl_down(p, off, 64);
    if (lane == 0) out[wave] = p * (1.0f / 9.0f);
}

extern "C" void kernel_launch(void* const* d_in, const int* in_sizes, int n_in,
                              void* d_out, int out_size, void* d_ws, size_t ws_size,
                              hipStream_t stream) {
    const float* user_emb = (const float*)d_in[0];
    const float* item_emb = (const float*)d_in[1];
    const float* cat_emb  = (const float*)d_in[2];
    const float* g_vals   = (const float*)d_in[3];
    const float* gx_vals  = (const float*)d_in[4];
    const int* g_rows  = (const int*)d_in[5];
    const int* g_cols  = (const int*)d_in[6];
    const int* gx_rows = (const int*)d_in[7];
    const int* gx_cols = (const int*)d_in[8];
    const int* train_users = (const int*)d_in[9];
    const int* train_items = (const int*)d_in[10];
    const int* i2c   = (const int*)d_in[11];
    const int* users = (const int*)d_in[12];
    const int* items = (const int*)d_in[13];
    float* out = (float*)d_out;

    char* ws = (char*)d_ws;
    size_t off = 0;
    auto alloc = [&](size_t bytes) -> void* {
        void* p = ws + off;
        off += (bytes + 255) & ~(size_t)255;
        return p;
    };
    const size_t NB = (size_t)N_NODES * D * sizeof(float);  // 25.6 MB
    float* x    = (float*)alloc(NB);
    float* t    = (float*)alloc(NB);
    float* accb = (float*)alloc(NB);
    float* dinv = (float*)alloc((size_t)N_NODES * sizeof(float));
    int*  cntC  = (int*)alloc((size_t)2 * NBKT * sizeof(int));  // cntC | cntG adjacent
    int*  cntG  = cntC + NBKT;
    int*  offC  = (int*)alloc((size_t)(NBKT + 1) * sizeof(int));
    int*  curC  = (int*)alloc((size_t)NBKT * sizeof(int));
    int*  offG  = (int*)alloc((size_t)(NBKT + 1) * sizeof(int));
    int*  curG  = (int*)alloc((size_t)NBKT * sizeof(int));
    int*  rowC  = (int*)alloc((size_t)(N_NODES + 1) * sizeof(int));
    int*  rowG  = (int*)alloc((size_t)(N_NODES + 1) * sizeof(int));
    int2* edgeCr = (int2*)alloc((size_t)2 * NNZ_GX * sizeof(int2));  // 32 MB raw
    int2* edgeCs = (int2*)alloc((size_t)2 * NNZ_GX * sizeof(int2));  // 32 MB sorted
    int2* edgeGr = (int2*)alloc((size_t)NNZ_G * sizeof(int2));       // 8 MB raw
    int2* edgeGs = (int2*)alloc((size_t)NNZ_G * sizeof(int2));       // 8 MB sorted

    // init
    hipMemcpyAsync(x, user_emb, (size_t)NUM_USERS * D * sizeof(float),
                   hipMemcpyDeviceToDevice, stream);
    hipMemcpyAsync(x + (size_t)NUM_USERS * D, item_emb,
                   (size_t)NUM_ITEMS * D * sizeof(float),
                   hipMemcpyDeviceToDevice, stream);
    hipMemsetAsync(accb, 0, NB, stream);
    hipMemsetAsync(dinv, 0, (size_t)N_NODES * sizeof(float), stream);
    hipMemsetAsync(cntC, 0, (size_t)2 * NBKT * sizeof(int), stream);

    deg_kernel<<<(N_EDGES + 255) / 256, 256, 0, stream>>>(train_users, train_items, dinv);
    dinv_kernel<<<(N_NODES + 255) / 256, 256, 0, stream>>>(dinv);

    hist_both_kernel<<<256, 256, 0, stream>>>(gx_rows, train_users, train_items, g_rows,
                                              cntC, cntG);
    scan2_kernel<<<2, 1024, 0, stream>>>(cntC, offC, curC, rowC, cntG, offG, curG, rowG);
    append_c_kernel<<<(NNZ_GX + 255) / 256, 256, 0, stream>>>(gx_rows, gx_cols, gx_vals,
                                                              train_users, train_items, i2c,
                                                              curC, edgeCr);
    append_g_kernel<<<(NNZ_G + 255) / 256, 256, 0, stream>>>(g_rows, g_cols, g_vals,
                                                             curG, edgeGr);
    sort_c_kernel<<<NBKT, 256, 0, stream>>>(offC, edgeCr, edgeCs, rowC);
    sort_g_kernel<<<NBKT, 256, 0, stream>>>(offG, edgeGr, edgeGs, rowG);

    const int pull_grid = (N_NODES * 64 + 255) / 256;
    for (int layer = 0; layer < N_LAYERS; ++layer) {
        pull_g_kernel<<<pull_grid, 256, 0, stream>>>(rowG, edgeGs, x, t);
        if (layer == 0)
            pull_c_fused<1><<<pull_grid, 256, 0, stream>>>(rowC, edgeCs, cat_emb, t, dinv, x, accb);
        else
            pull_c_fused<0><<<pull_grid, 256, 0, stream>>>(rowC, edgeCs, cat_emb, t, dinv, x, accb);
    }

    gamma_kernel<<<(BATCH * 64 + 255) / 256, 256, 0, stream>>>(users, items, accb, out);
}

// Round 5
// 945.246 us; speedup vs baseline: 13.7322x; 1.0774x over previous
//
#include <hip/hip_runtime.h>

#define NUM_USERS 50000
#define NUM_ITEMS 50000
#define NUM_CATS  500
#define D         64
#define N_LAYERS  3
#define N_EDGES   500000
#define NNZ_G     1000000
#define NNZ_GX    2000000
#define BATCH     8192
#define N_NODES   (NUM_USERS + NUM_ITEMS)

// G-path (old) fine buckets
#define BKT_SHIFT 4
#define BKT_W     16
#define NBKT      (N_NODES / BKT_W)   // 6250

// C-path super-buckets
#define SB_SHIFT  9
#define SB_W      512
#define NSB       ((N_NODES + SB_W - 1) / SB_W)   // 196
#define P1_K      15
#define P1_TILE   (256 * P1_K)        // 3840 nnz per WG
#define P1_REC    (2 * P1_TILE)       // 7680 records

// ---------- degree ----------
__global__ void deg_kernel(const int* __restrict__ tu, const int* __restrict__ ti,
                           float* __restrict__ deg) {
    int e = blockIdx.x * blockDim.x + threadIdx.x;
    if (e >= N_EDGES) return;
    unsafeAtomicAdd(deg + tu[e], 1.0f);
    unsafeAtomicAdd(deg + NUM_USERS + ti[e], 1.0f);
}

__global__ void dinv_kernel(float* __restrict__ deg) {
    int n = blockIdx.x * blockDim.x + threadIdx.x;
    if (n < N_NODES) deg[n] = 1.0f / (deg[n] + 1e-9f);
}

// ---------- C: super-bucket histogram ----------
__global__ void histsb_c_kernel(const int* __restrict__ gx_rows,
                                const int* __restrict__ tu, const int* __restrict__ ti,
                                int* __restrict__ cnt) {
    __shared__ int h[NSB];
    for (int i = threadIdx.x; i < NSB; i += blockDim.x) h[i] = 0;
    __syncthreads();
    int stride = gridDim.x * blockDim.x;
    for (int j = blockIdx.x * blockDim.x + threadIdx.x; j < NNZ_GX; j += stride) {
        int r = gx_rows[j];
        atomicAdd(h + (tu[r] >> SB_SHIFT), 1);
        atomicAdd(h + ((NUM_USERS + ti[r]) >> SB_SHIFT), 1);
    }
    __syncthreads();
    for (int i = threadIdx.x; i < NSB; i += blockDim.x)
        if (h[i]) atomicAdd(cnt + i, h[i]);
}

// ---------- C: tiny scan over 196 super-buckets ----------
__global__ void scansb_kernel(const int* __restrict__ cnt, int* __restrict__ off,
                              int* __restrict__ cur, int* __restrict__ row_sentinel) {
    __shared__ int s[NSB];
    int t = threadIdx.x;
    if (t < NSB) s[t] = cnt[t];
    __syncthreads();
    if (t == 0) {
        int run = 0;
        for (int i = 0; i < NSB; ++i) { off[i] = run; cur[i] = run; run += s[i]; }
        off[NSB] = run;
        row_sentinel[0] = run;
    }
}

// ---------- C phase 1: WG multisplit append into super-buckets ----------
// record: e.x = (dst<<15) | (src & 0x7FFF)
//         e.y = (vbf16<<16) | ((src>>15)&3)<<10 | (cat<<1) | half
__global__ void __launch_bounds__(256) p1c_kernel(
        const int* __restrict__ gx_rows, const int* __restrict__ gx_cols,
        const float* __restrict__ gx_vals,
        const int* __restrict__ tu, const int* __restrict__ ti,
        const int* __restrict__ i2c,
        int* __restrict__ sbcur, int2* __restrict__ out) {
    __shared__ int2 recs[P1_REC];                 // 60 KB
    __shared__ int h[NSB], base[NSB], cur[NSB];
    int t = threadIdx.x;
    for (int i = t; i < NSB; i += 256) { h[i] = 0; cur[i] = 0; }
    __syncthreads();
    int tb = blockIdx.x * P1_TILE;
    #pragma unroll
    for (int k = 0; k < P1_K; ++k) {
        int l = t + k * 256;
        int j = tb + l;
        if (j < NNZ_GX) {
            int r = gx_rows[j], c = gx_cols[j];
            unsigned u = __float_as_uint(gx_vals[j]);
            unsigned vb = (u + 0x7FFFu + ((u >> 16) & 1u)) >> 16;   // RNE f32->bf16
            int tur = tu[r], tir = ti[r], tuc = tu[c], tic = ti[c];
            int cat = i2c[tic];
            int ylo = (int)(vb << 16) | (cat << 1);
            unsigned dstu = (unsigned)tur;           int srcu = tuc;
            unsigned dsti = (unsigned)(NUM_USERS + tir); int srci = NUM_USERS + tic;
            recs[2 * l] = make_int2((int)((dstu << 15) | (unsigned)(srcu & 0x7FFF)),
                                    ylo | (((srcu >> 15) & 3) << 10));
            recs[2 * l + 1] = make_int2((int)((dsti << 15) | (unsigned)(srci & 0x7FFF)),
                                        ylo | (((srci >> 15) & 3) << 10) | 1);
            atomicAdd(h + (int)(dstu >> SB_SHIFT), 1);
            atomicAdd(h + (int)(dsti >> SB_SHIFT), 1);
        }
    }
    __syncthreads();
    if (t < NSB) base[t] = atomicAdd(sbcur + t, h[t]);
    __syncthreads();
    int rem = NNZ_GX - tb;
    int nrec = 2 * (rem < P1_TILE ? rem : P1_TILE);
    for (int s = t; s < nrec; s += 256) {
        int2 rec = recs[s];
        int bkt = (int)(((unsigned)rec.x) >> 24);   // dst>>9
        int p = base[bkt] + atomicAdd(cur + bkt, 1);
        out[p] = rec;
    }
}

// ---------- C phase 2: per-super-bucket node sort, emits rowC ----------
__global__ void __launch_bounds__(512) p2c_kernel(
        const int* __restrict__ sboff, const int2* __restrict__ raw,
        int2* __restrict__ sorted, int* __restrict__ rowC) {
    int b = blockIdx.x;
    int beg = sboff[b], end = sboff[b + 1];
    __shared__ int h[SB_W], cur[SB_W];
    int t = threadIdx.x;
    h[t] = 0;
    __syncthreads();
    for (int i = beg + t; i < end; i += 512)
        atomicAdd(h + (int)((((unsigned)raw[i].x) >> 15) & (SB_W - 1)), 1);
    __syncthreads();
    int cnt = h[t];
    // inclusive Hillis-Steele scan of h
    for (int o = 1; o < SB_W; o <<= 1) {
        int tmp = (t >= o) ? h[t - o] : 0;
        __syncthreads();
        h[t] += tmp;
        __syncthreads();
    }
    int excl = h[t] - cnt;
    cur[t] = beg + excl;
    int node = b * SB_W + t;
    if (node < N_NODES) rowC[node] = beg + excl;
    __syncthreads();
    for (int i = beg + t; i < end; i += 512) {
        int2 e = raw[i];
        unsigned rx = (unsigned)e.x;
        int dl = (int)((rx >> 15) & (SB_W - 1));
        int src = (int)(rx & 0x7FFF) | (((e.y >> 10) & 3) << 15);
        int p = atomicAdd(cur + dl, 1);
        sorted[p] = make_int2((src << 10) | (e.y & 0x3FF), e.y & 0xFFFF0000);
    }
}

// ---------- G path (unchanged from R4) ----------
__global__ void histg_kernel(const int* __restrict__ g_rows, int* __restrict__ cnt) {
    __shared__ int h[NBKT];
    for (int i = threadIdx.x; i < NBKT; i += blockDim.x) h[i] = 0;
    __syncthreads();
    int stride = gridDim.x * blockDim.x;
    for (int e = blockIdx.x * blockDim.x + threadIdx.x; e < NNZ_G; e += stride)
        atomicAdd(h + (g_rows[e] >> BKT_SHIFT), 1);
    __syncthreads();
    for (int i = threadIdx.x; i < NBKT; i += blockDim.x)
        if (h[i]) atomicAdd(cnt + i, h[i]);
}

__global__ void scang_kernel(const int* __restrict__ cnt, int* __restrict__ off,
                             int* __restrict__ cur, int* __restrict__ row) {
    __shared__ int sums[1024];
    const int T = 1024;
    const int strip = (NBKT + T - 1) / T;
    int t = threadIdx.x;
    int beg = t * strip;
    int end = beg + strip; if (end > NBKT) end = NBKT;
    int s = 0;
    for (int i = beg; i < end; ++i) s += cnt[i];
    sums[t] = s;
    __syncthreads();
    if (t == 0) {
        int run = 0;
        for (int i = 0; i < T; ++i) { int v = sums[i]; sums[i] = run; run += v; }
        off[NBKT] = run;
        row[N_NODES] = run;
    }
    __syncthreads();
    int run = sums[t];
    for (int i = beg; i < end; ++i) { off[i] = run; cur[i] = run; run += cnt[i]; }
}

__global__ void append_g_kernel(const int* __restrict__ g_rows, const int* __restrict__ g_cols,
                                const float* __restrict__ g_vals,
                                int* __restrict__ cur, int2* __restrict__ edges) {
    int e = blockIdx.x * blockDim.x + threadIdx.x;
    if (e >= NNZ_G) return;
    int dst = g_rows[e];
    int p = atomicAdd(cur + (dst >> BKT_SHIFT), 1);
    edges[p] = make_int2(((dst & (BKT_W - 1)) << 17) | g_cols[e], __float_as_int(g_vals[e]));
}

__global__ void sort_g_kernel(const int* __restrict__ off, const int2* __restrict__ raw,
                              int2* __restrict__ sorted, int* __restrict__ rowG) {
    int b = blockIdx.x;
    int base = off[b], end = off[b + 1];
    __shared__ int hist[BKT_W], cur[BKT_W], scn[BKT_W];
    if (threadIdx.x < BKT_W) hist[threadIdx.x] = 0;
    __syncthreads();
    for (int i = base + threadIdx.x; i < end; i += blockDim.x)
        atomicAdd(hist + ((raw[i].x >> 17) & 15), 1);
    __syncthreads();
    if (threadIdx.x == 0) {
        int run = 0;
        for (int k = 0; k < BKT_W; ++k) { scn[k] = run; cur[k] = run; run += hist[k]; }
    }
    __syncthreads();
    if (threadIdx.x < BKT_W) rowG[b * BKT_W + threadIdx.x] = base + scn[threadIdx.x];
    for (int i = base + threadIdx.x; i < end; i += blockDim.x) {
        int2 e = raw[i];
        int dl = (e.x >> 17) & 15;
        int p = atomicAdd(cur + dl, 1);
        sorted[base + p] = make_int2((e.x & 0x1FFFF) << 6, e.y);  // src*64
    }
}

// ---------- pull SpMM (G): one wave per dst node, 16 lanes/edge, float4 ----------
__global__ void pull_g_kernel(const int* __restrict__ row, const int2* __restrict__ edges,
                              const float* __restrict__ x, float* __restrict__ out) {
    int wave = (blockIdx.x * blockDim.x + threadIdx.x) >> 6;
    int lane = threadIdx.x & 63;
    if (wave >= N_NODES) return;
    int eg = lane >> 4;
    int q  = lane & 15;
    int beg = row[wave], end = row[wave + 1];
    float4 acc = make_float4(0.f, 0.f, 0.f, 0.f);
    #pragma unroll 2
    for (int i = beg + eg; i < end; i += 4) {
        int2 e = edges[i];
        float v = __int_as_float(e.y);
        float4 xv = *(const float4*)(x + e.x + q * 4);
        acc.x += v * xv.x; acc.y += v * xv.y; acc.z += v * xv.z; acc.w += v * xv.w;
    }
    acc.x += __shfl_xor(acc.x, 16, 64); acc.y += __shfl_xor(acc.y, 16, 64);
    acc.z += __shfl_xor(acc.z, 16, 64); acc.w += __shfl_xor(acc.w, 16, 64);
    acc.x += __shfl_xor(acc.x, 32, 64); acc.y += __shfl_xor(acc.y, 32, 64);
    acc.z += __shfl_xor(acc.z, 32, 64); acc.w += __shfl_xor(acc.w, 32, 64);
    if (lane < 16) *(float4*)(out + (size_t)wave * D + q * 4) = acc;
}

// ---------- pull SpMM (C) fused with finalize ----------
template <int LAYER0>
__global__ void pull_c_fused(const int* __restrict__ row, const int2* __restrict__ edges,
                             const float* __restrict__ catbase,
                             const float* __restrict__ t, const float* __restrict__ dinv,
                             float* __restrict__ x, float* __restrict__ accb) {
    int wave = (blockIdx.x * blockDim.x + threadIdx.x) >> 6;
    int lane = threadIdx.x & 63;
    if (wave >= N_NODES) return;
    int eg = lane >> 4;
    int q  = lane & 15;
    int beg = row[wave], end = row[wave + 1];
    float4 acc = make_float4(0.f, 0.f, 0.f, 0.f);
    #pragma unroll 2
    for (int i = beg + eg; i < end; i += 4) {
        int2 e = edges[i];
        float v = __int_as_float(e.y);
        int src = e.x >> 10;
        float4 xv = *(const float4*)(t + src * D + q * 4);
        if (LAYER0) {
            int code = e.x & 1023;  // (cat<<1)|half
            int catoff = (code >> 1) * (2 * D) + ((code & 1) << 6);
            const float4 cv = *(const float4*)(catbase + catoff + q * 4);
            xv.x += cv.x; xv.y += cv.y; xv.z += cv.z; xv.w += cv.w;
        }
        acc.x += v * xv.x; acc.y += v * xv.y; acc.z += v * xv.z; acc.w += v * xv.w;
    }
    acc.x += __shfl_xor(acc.x, 16, 64); acc.y += __shfl_xor(acc.y, 16, 64);
    acc.z += __shfl_xor(acc.z, 16, 64); acc.w += __shfl_xor(acc.w, 16, 64);
    acc.x += __shfl_xor(acc.x, 32, 64); acc.y += __shfl_xor(acc.y, 32, 64);
    acc.z += __shfl_xor(acc.z, 32, 64); acc.w += __shfl_xor(acc.w, 32, 64);
    if (lane < 16) {
        float di = dinv[wave];
        size_t o = (size_t)wave * D + q * 4;
        float4 tv = *(const float4*)(t + o);
        float4 nx;
        nx.x = (acc.x * di + tv.x) * 0.5f;
        nx.y = (acc.y * di + tv.y) * 0.5f;
        nx.z = (acc.z * di + tv.z) * 0.5f;
        nx.w = (acc.w * di + tv.w) * 0.5f;
        *(float4*)(x + o) = nx;
        float4 av = *(const float4*)(accb + o);
        av.x += nx.x; av.y += nx.y; av.z += nx.z; av.w += nx.w;
        *(float4*)(accb + o) = av;
    }
}

// ---------- gamma ----------
__global__ void gamma_kernel(const int* __restrict__ users, const int* __restrict__ items,
                             const float* __restrict__ acc, float* __restrict__ out) {
    int wave = (blockIdx.x * blockDim.x + threadIdx.x) >> 6;
    int lane = threadIdx.x & 63;
    if (wave >= BATCH) return;
    int u = users[wave], it = items[wave];
    float p = acc[(size_t)u * D + lane] * acc[(size_t)(NUM_USERS + it) * D + lane];
#pragma unroll
    for (int off = 32; off > 0; off >>= 1) p += __shfl_down(p, off, 64);
    if (lane == 0) out[wave] = p * (1.0f / 9.0f);
}

extern "C" void kernel_launch(void* const* d_in, const int* in_sizes, int n_in,
                              void* d_out, int out_size, void* d_ws, size_t ws_size,
                              hipStream_t stream) {
    const float* user_emb = (const float*)d_in[0];
    const float* item_emb = (const float*)d_in[1];
    const float* cat_emb  = (const float*)d_in[2];
    const float* g_vals   = (const float*)d_in[3];
    const float* gx_vals  = (const float*)d_in[4];
    const int* g_rows  = (const int*)d_in[5];
    const int* g_cols  = (const int*)d_in[6];
    const int* gx_rows = (const int*)d_in[7];
    const int* gx_cols = (const int*)d_in[8];
    const int* train_users = (const int*)d_in[9];
    const int* train_items = (const int*)d_in[10];
    const int* i2c   = (const int*)d_in[11];
    const int* users = (const int*)d_in[12];
    const int* items = (const int*)d_in[13];
    float* out = (float*)d_out;

    char* ws = (char*)d_ws;
    size_t off = 0;
    auto alloc = [&](size_t bytes) -> void* {
        void* p = ws + off;
        off += (bytes + 255) & ~(size_t)255;
        return p;
    };
    const size_t NB = (size_t)N_NODES * D * sizeof(float);  // 25.6 MB
    float* x    = (float*)alloc(NB);
    float* t    = (float*)alloc(NB);
    float* accb = (float*)alloc(NB);
    float* dinv = (float*)alloc((size_t)N_NODES * sizeof(float));
    int*  sbhC  = (int*)alloc((size_t)NSB * sizeof(int));
    int*  sboffC= (int*)alloc((size_t)(NSB + 1) * sizeof(int));
    int*  sbcurC= (int*)alloc((size_t)NSB * sizeof(int));
    int*  cntG  = (int*)alloc((size_t)NBKT * sizeof(int));
    int*  offG  = (int*)alloc((size_t)(NBKT + 1) * sizeof(int));
    int*  curG  = (int*)alloc((size_t)NBKT * sizeof(int));
    int*  rowC  = (int*)alloc((size_t)(N_NODES + 1) * sizeof(int));
    int*  rowG  = (int*)alloc((size_t)(N_NODES + 1) * sizeof(int));
    int2* edgeCr = (int2*)alloc((size_t)2 * NNZ_GX * sizeof(int2));  // 32 MB raw
    int2* edgeCs = (int2*)alloc((size_t)2 * NNZ_GX * sizeof(int2));  // 32 MB sorted
    int2* edgeGr = (int2*)alloc((size_t)NNZ_G * sizeof(int2));       // 8 MB raw
    int2* edgeGs = (int2*)alloc((size_t)NNZ_G * sizeof(int2));       // 8 MB sorted

    // init
    hipMemcpyAsync(x, user_emb, (size_t)NUM_USERS * D * sizeof(float),
                   hipMemcpyDeviceToDevice, stream);
    hipMemcpyAsync(x + (size_t)NUM_USERS * D, item_emb,
                   (size_t)NUM_ITEMS * D * sizeof(float),
                   hipMemcpyDeviceToDevice, stream);
    hipMemsetAsync(accb, 0, NB, stream);
    hipMemsetAsync(dinv, 0, (size_t)N_NODES * sizeof(float), stream);
    hipMemsetAsync(sbhC, 0, (size_t)NSB * sizeof(int), stream);
    hipMemsetAsync(cntG, 0, (size_t)NBKT * sizeof(int), stream);

    deg_kernel<<<(N_EDGES + 255) / 256, 256, 0, stream>>>(train_users, train_items, dinv);
    dinv_kernel<<<(N_NODES + 255) / 256, 256, 0, stream>>>(dinv);

    // C build: super-bucket hist -> scan -> WG-multisplit append -> per-bucket node sort
    histsb_c_kernel<<<256, 256, 0, stream>>>(gx_rows, train_users, train_items, sbhC);
    scansb_kernel<<<1, 256, 0, stream>>>(sbhC, sboffC, sbcurC, rowC + N_NODES);
    p1c_kernel<<<(NNZ_GX + P1_TILE - 1) / P1_TILE, 256, 0, stream>>>(
        gx_rows, gx_cols, gx_vals, train_users, train_items, i2c, sbcurC, edgeCr);
    p2c_kernel<<<NSB, 512, 0, stream>>>(sboffC, edgeCr, edgeCs, rowC);

    // G build (old path)
    histg_kernel<<<256, 256, 0, stream>>>(g_rows, cntG);
    scang_kernel<<<1, 1024, 0, stream>>>(cntG, offG, curG, rowG);
    append_g_kernel<<<(NNZ_G + 255) / 256, 256, 0, stream>>>(g_rows, g_cols, g_vals,
                                                             curG, edgeGr);
    sort_g_kernel<<<NBKT, 256, 0, stream>>>(offG, edgeGr, edgeGs, rowG);

    const int pull_grid = (N_NODES * 64 + 255) / 256;
    for (int layer = 0; layer < N_LAYERS; ++layer) {
        pull_g_kernel<<<pull_grid, 256, 0, stream>>>(rowG, edgeGs, x, t);
        if (layer == 0)
            pull_c_fused<1><<<pull_grid, 256, 0, stream>>>(rowC, edgeCs, cat_emb, t, dinv, x, accb);
        else
            pull_c_fused<0><<<pull_grid, 256, 0, stream>>>(rowC, edgeCs, cat_emb, t, dinv, x, accb);
    }

    gamma_kernel<<<(BATCH * 64 + 255) / 256, 256, 0, stream>>>(users, items, accb, out);
}

// Round 6
// 856.251 us; speedup vs baseline: 15.1595x; 1.1039x over previous
//
#include <hip/hip_runtime.h>

#define NUM_USERS 50000
#define NUM_ITEMS 50000
#define NUM_CATS  500
#define D         64
#define N_LAYERS  3
#define N_EDGES   500000
#define NNZ_G     1000000
#define NNZ_GX    2000000
#define BATCH     8192
#define N_NODES   (NUM_USERS + NUM_ITEMS)

// G-path fine buckets
#define BKT_SHIFT 4
#define BKT_W     16
#define NBKT      (N_NODES / BKT_W)   // 6250

// C-path super-buckets
#define SB_SHIFT  9
#define SB_W      512
#define NSB       ((N_NODES + SB_W - 1) / SB_W)   // 196
#define P1_K      15
#define P1_TILE   (256 * P1_K)        // 3840 nnz per WG
#define P1_REC    (2 * P1_TILE)       // 7680 records

__device__ __forceinline__ unsigned bf16rne(float f) {
    unsigned u = __float_as_uint(f);
    return (u + 0x7FFFu + ((u >> 16) & 1u)) >> 16;
}
__device__ __forceinline__ float4 bf16x4_to_f4(uint2 w) {
    float4 r;
    r.x = __uint_as_float(w.x << 16);
    r.y = __uint_as_float(w.x & 0xFFFF0000u);
    r.z = __uint_as_float(w.y << 16);
    r.w = __uint_as_float(w.y & 0xFFFF0000u);
    return r;
}

// ---------- degree ----------
__global__ void deg_kernel(const int* __restrict__ tu, const int* __restrict__ ti,
                           float* __restrict__ deg) {
    int e = blockIdx.x * blockDim.x + threadIdx.x;
    if (e >= N_EDGES) return;
    unsafeAtomicAdd(deg + tu[e], 1.0f);
    unsafeAtomicAdd(deg + NUM_USERS + ti[e], 1.0f);
}

__global__ void dinv_kernel(float* __restrict__ deg) {
    int n = blockIdx.x * blockDim.x + threadIdx.x;
    if (n < N_NODES) deg[n] = 1.0f / (deg[n] + 1e-9f);
}

// ---------- init x (f32 + bf16 shadow) ----------
__global__ void init_x_kernel(const float* __restrict__ ue, const float* __restrict__ ie,
                              float* __restrict__ xf, ushort* __restrict__ xb) {
    int i4 = blockIdx.x * blockDim.x + threadIdx.x;   // float4 index
    if (i4 >= N_NODES * D / 4) return;
    const int half = NUM_USERS * D / 4;
    float4 v = (i4 < half) ? ((const float4*)ue)[i4] : ((const float4*)ie)[i4 - half];
    ((float4*)xf)[i4] = v;
    uint2 p;
    p.x = bf16rne(v.x) | (bf16rne(v.y) << 16);
    p.y = bf16rne(v.z) | (bf16rne(v.w) << 16);
    ((uint2*)xb)[i4] = p;
}

// ---------- C: super-bucket histogram ----------
__global__ void histsb_c_kernel(const int* __restrict__ gx_rows,
                                const int* __restrict__ tu, const int* __restrict__ ti,
                                int* __restrict__ cnt) {
    __shared__ int h[NSB];
    for (int i = threadIdx.x; i < NSB; i += blockDim.x) h[i] = 0;
    __syncthreads();
    int stride = gridDim.x * blockDim.x;
    for (int j = blockIdx.x * blockDim.x + threadIdx.x; j < NNZ_GX; j += stride) {
        int r = gx_rows[j];
        atomicAdd(h + (tu[r] >> SB_SHIFT), 1);
        atomicAdd(h + ((NUM_USERS + ti[r]) >> SB_SHIFT), 1);
    }
    __syncthreads();
    for (int i = threadIdx.x; i < NSB; i += blockDim.x)
        if (h[i]) atomicAdd(cnt + i, h[i]);
}

// ---------- C: tiny scan over 196 super-buckets ----------
__global__ void scansb_kernel(const int* __restrict__ cnt, int* __restrict__ off,
                              int* __restrict__ cur, int* __restrict__ row_sentinel) {
    int t = threadIdx.x;
    if (t == 0) {
        int run = 0;
        for (int i = 0; i < NSB; ++i) { off[i] = run; cur[i] = run; run += cnt[i]; }
        off[NSB] = run;
        row_sentinel[0] = run;
    }
}

// ---------- C phase 1: WG multisplit append into super-buckets ----------
__global__ void __launch_bounds__(256) p1c_kernel(
        const int* __restrict__ gx_rows, const int* __restrict__ gx_cols,
        const float* __restrict__ gx_vals,
        const int* __restrict__ tu, const int* __restrict__ ti,
        const int* __restrict__ i2c,
        int* __restrict__ sbcur, int2* __restrict__ out) {
    __shared__ int2 recs[P1_REC];                 // 60 KB
    __shared__ int h[NSB], base[NSB], cur[NSB];
    int t = threadIdx.x;
    for (int i = t; i < NSB; i += 256) { h[i] = 0; cur[i] = 0; }
    __syncthreads();
    int tb = blockIdx.x * P1_TILE;
    #pragma unroll
    for (int k = 0; k < P1_K; ++k) {
        int l = t + k * 256;
        int j = tb + l;
        if (j < NNZ_GX) {
            int r = gx_rows[j], c = gx_cols[j];
            unsigned vb = bf16rne(gx_vals[j]);
            int tur = tu[r], tir = ti[r], tuc = tu[c], tic = ti[c];
            int cat = i2c[tic];
            int ylo = (int)(vb << 16) | (cat << 1);
            unsigned dstu = (unsigned)tur;           int srcu = tuc;
            unsigned dsti = (unsigned)(NUM_USERS + tir); int srci = NUM_USERS + tic;
            recs[2 * l] = make_int2((int)((dstu << 15) | (unsigned)(srcu & 0x7FFF)),
                                    ylo | (((srcu >> 15) & 3) << 10));
            recs[2 * l + 1] = make_int2((int)((dsti << 15) | (unsigned)(srci & 0x7FFF)),
                                        ylo | (((srci >> 15) & 3) << 10) | 1);
            atomicAdd(h + (int)(dstu >> SB_SHIFT), 1);
            atomicAdd(h + (int)(dsti >> SB_SHIFT), 1);
        }
    }
    __syncthreads();
    if (t < NSB) base[t] = atomicAdd(sbcur + t, h[t]);
    __syncthreads();
    int rem = NNZ_GX - tb;
    int nrec = 2 * (rem < P1_TILE ? rem : P1_TILE);
    for (int s = t; s < nrec; s += 256) {
        int2 rec = recs[s];
        int bkt = (int)(((unsigned)rec.x) >> 24);   // dst>>9
        int p = base[bkt] + atomicAdd(cur + bkt, 1);
        out[p] = rec;
    }
}

// ---------- C phase 2: per-super-bucket node sort, emits rowC ----------
__global__ void __launch_bounds__(512) p2c_kernel(
        const int* __restrict__ sboff, const int2* __restrict__ raw,
        int2* __restrict__ sorted, int* __restrict__ rowC) {
    int b = blockIdx.x;
    int beg = sboff[b], end = sboff[b + 1];
    __shared__ int h[SB_W], cur[SB_W];
    int t = threadIdx.x;
    h[t] = 0;
    __syncthreads();
    for (int i = beg + t; i < end; i += 512)
        atomicAdd(h + (int)((((unsigned)raw[i].x) >> 15) & (SB_W - 1)), 1);
    __syncthreads();
    int cnt = h[t];
    for (int o = 1; o < SB_W; o <<= 1) {
        int tmp = (t >= o) ? h[t - o] : 0;
        __syncthreads();
        h[t] += tmp;
        __syncthreads();
    }
    int excl = h[t] - cnt;
    cur[t] = beg + excl;
    int node = b * SB_W + t;
    if (node < N_NODES) rowC[node] = beg + excl;
    __syncthreads();
    for (int i = beg + t; i < end; i += 512) {
        int2 e = raw[i];
        unsigned rx = (unsigned)e.x;
        int dl = (int)((rx >> 15) & (SB_W - 1));
        int src = (int)(rx & 0x7FFF) | (((e.y >> 10) & 3) << 15);
        int p = atomicAdd(cur + dl, 1);
        sorted[p] = make_int2((src << 10) | (e.y & 0x3FF), e.y & 0xFFFF0000);
    }
}

// ---------- G path ----------
__global__ void histg_kernel(const int* __restrict__ g_rows, int* __restrict__ cnt) {
    __shared__ int h[NBKT];
    for (int i = threadIdx.x; i < NBKT; i += blockDim.x) h[i] = 0;
    __syncthreads();
    int stride = gridDim.x * blockDim.x;
    for (int e = blockIdx.x * blockDim.x + threadIdx.x; e < NNZ_G; e += stride)
        atomicAdd(h + (g_rows[e] >> BKT_SHIFT), 1);
    __syncthreads();
    for (int i = threadIdx.x; i < NBKT; i += blockDim.x)
        if (h[i]) atomicAdd(cnt + i, h[i]);
}

__global__ void scang_kernel(const int* __restrict__ cnt, int* __restrict__ off,
                             int* __restrict__ cur, int* __restrict__ row) {
    __shared__ int sums[1024];
    const int T = 1024;
    const int strip = (NBKT + T - 1) / T;
    int t = threadIdx.x;
    int beg = t * strip;
    int end = beg + strip; if (end > NBKT) end = NBKT;
    int s = 0;
    for (int i = beg; i < end; ++i) s += cnt[i];
    sums[t] = s;
    __syncthreads();
    if (t == 0) {
        int run = 0;
        for (int i = 0; i < T; ++i) { int v = sums[i]; sums[i] = run; run += v; }
        off[NBKT] = run;
        row[N_NODES] = run;
    }
    __syncthreads();
    int run = sums[t];
    for (int i = beg; i < end; ++i) { off[i] = run; cur[i] = run; run += cnt[i]; }
}

__global__ void append_g_kernel(const int* __restrict__ g_rows, const int* __restrict__ g_cols,
                                const float* __restrict__ g_vals,
                                int* __restrict__ cur, int2* __restrict__ edges) {
    int e = blockIdx.x * blockDim.x + threadIdx.x;
    if (e >= NNZ_G) return;
    int dst = g_rows[e];
    int p = atomicAdd(cur + (dst >> BKT_SHIFT), 1);
    edges[p] = make_int2(((dst & (BKT_W - 1)) << 17) | g_cols[e], __float_as_int(g_vals[e]));
}

__global__ void sort_g_kernel(const int* __restrict__ off, const int2* __restrict__ raw,
                              int2* __restrict__ sorted, int* __restrict__ rowG) {
    int b = blockIdx.x;
    int base = off[b], end = off[b + 1];
    __shared__ int hist[BKT_W], cur[BKT_W], scn[BKT_W];
    if (threadIdx.x < BKT_W) hist[threadIdx.x] = 0;
    __syncthreads();
    for (int i = base + threadIdx.x; i < end; i += blockDim.x)
        atomicAdd(hist + ((raw[i].x >> 17) & 15), 1);
    __syncthreads();
    if (threadIdx.x == 0) {
        int run = 0;
        for (int k = 0; k < BKT_W; ++k) { scn[k] = run; cur[k] = run; run += hist[k]; }
    }
    __syncthreads();
    if (threadIdx.x < BKT_W) rowG[b * BKT_W + threadIdx.x] = base + scn[threadIdx.x];
    for (int i = base + threadIdx.x; i < end; i += blockDim.x) {
        int2 e = raw[i];
        int dl = (e.x >> 17) & 15;
        int p = atomicAdd(cur + dl, 1);
        sorted[base + p] = make_int2((e.x & 0x1FFFF) << 6, e.y);  // src*64 (element index)
    }
}

// ---------- pull SpMM (G): gathers bf16 x, writes f32 + bf16 t ----------
__global__ void pull_g_kernel(const int* __restrict__ row, const int2* __restrict__ edges,
                              const ushort* __restrict__ xb,
                              float* __restrict__ tf, ushort* __restrict__ tb) {
    int wave = (blockIdx.x * blockDim.x + threadIdx.x) >> 6;
    int lane = threadIdx.x & 63;
    if (wave >= N_NODES) return;
    int eg = lane >> 4;
    int q  = lane & 15;
    int beg = row[wave], end = row[wave + 1];
    float4 acc = make_float4(0.f, 0.f, 0.f, 0.f);
    #pragma unroll 2
    for (int i = beg + eg; i < end; i += 4) {
        int2 e = edges[i];
        float v = __int_as_float(e.y);
        uint2 w = *(const uint2*)(xb + e.x + q * 4);
        float4 xv = bf16x4_to_f4(w);
        acc.x += v * xv.x; acc.y += v * xv.y; acc.z += v * xv.z; acc.w += v * xv.w;
    }
    acc.x += __shfl_xor(acc.x, 16, 64); acc.y += __shfl_xor(acc.y, 16, 64);
    acc.z += __shfl_xor(acc.z, 16, 64); acc.w += __shfl_xor(acc.w, 16, 64);
    acc.x += __shfl_xor(acc.x, 32, 64); acc.y += __shfl_xor(acc.y, 32, 64);
    acc.z += __shfl_xor(acc.z, 32, 64); acc.w += __shfl_xor(acc.w, 32, 64);
    if (lane < 16) {
        size_t o = (size_t)wave * D + q * 4;
        *(float4*)(tf + o) = acc;
        uint2 p;
        p.x = bf16rne(acc.x) | (bf16rne(acc.y) << 16);
        p.y = bf16rne(acc.z) | (bf16rne(acc.w) << 16);
        *(uint2*)(tb + o) = p;
    }
}

// ---------- pull SpMM (C) fused with finalize: gathers bf16 t ----------
template <int LAYER0>
__global__ void pull_c_fused(const int* __restrict__ row, const int2* __restrict__ edges,
                             const float* __restrict__ catbase,
                             const ushort* __restrict__ tb, const float* __restrict__ tf,
                             const float* __restrict__ dinv,
                             float* __restrict__ xf, ushort* __restrict__ xb,
                             float* __restrict__ accb) {
    int wave = (blockIdx.x * blockDim.x + threadIdx.x) >> 6;
    int lane = threadIdx.x & 63;
    if (wave >= N_NODES) return;
    int eg = lane >> 4;
    int q  = lane & 15;
    int beg = row[wave], end = row[wave + 1];
    float4 acc = make_float4(0.f, 0.f, 0.f, 0.f);
    #pragma unroll 2
    for (int i = beg + eg; i < end; i += 4) {
        int2 e = edges[i];
        float v = __int_as_float(e.y);
        int src = e.x >> 10;
        uint2 w = *(const uint2*)(tb + (size_t)src * D + q * 4);
        float4 xv = bf16x4_to_f4(w);
        if (LAYER0) {
            int code = e.x & 1023;  // (cat<<1)|half
            int catoff = (code >> 1) * (2 * D) + ((code & 1) << 6);
            const float4 cv = *(const float4*)(catbase + catoff + q * 4);
            xv.x += cv.x; xv.y += cv.y; xv.z += cv.z; xv.w += cv.w;
        }
        acc.x += v * xv.x; acc.y += v * xv.y; acc.z += v * xv.z; acc.w += v * xv.w;
    }
    acc.x += __shfl_xor(acc.x, 16, 64); acc.y += __shfl_xor(acc.y, 16, 64);
    acc.z += __shfl_xor(acc.z, 16, 64); acc.w += __shfl_xor(acc.w, 16, 64);
    acc.x += __shfl_xor(acc.x, 32, 64); acc.y += __shfl_xor(acc.y, 32, 64);
    acc.z += __shfl_xor(acc.z, 32, 64); acc.w += __shfl_xor(acc.w, 32, 64);
    if (lane < 16) {
        float di = dinv[wave];
        size_t o = (size_t)wave * D + q * 4;
        float4 tv = *(const float4*)(tf + o);
        float4 nx;
        nx.x = (acc.x * di + tv.x) * 0.5f;
        nx.y = (acc.y * di + tv.y) * 0.5f;
        nx.z = (acc.z * di + tv.z) * 0.5f;
        nx.w = (acc.w * di + tv.w) * 0.5f;
        *(float4*)(xf + o) = nx;
        uint2 p;
        p.x = bf16rne(nx.x) | (bf16rne(nx.y) << 16);
        p.y = bf16rne(nx.z) | (bf16rne(nx.w) << 16);
        *(uint2*)(xb + o) = p;
        float4 av = *(const float4*)(accb + o);
        av.x += nx.x; av.y += nx.y; av.z += nx.z; av.w += nx.w;
        *(float4*)(accb + o) = av;
    }
}

// ---------- gamma ----------
__global__ void gamma_kernel(const int* __restrict__ users, const int* __restrict__ items,
                             const float* __restrict__ acc, float* __restrict__ out) {
    int wave = (blockIdx.x * blockDim.x + threadIdx.x) >> 6;
    int lane = threadIdx.x & 63;
    if (wave >= BATCH) return;
    int u = users[wave], it = items[wave];
    float p = acc[(size_t)u * D + lane] * acc[(size_t)(NUM_USERS + it) * D + lane];
#pragma unroll
    for (int off = 32; off > 0; off >>= 1) p += __shfl_down(p, off, 64);
    if (lane == 0) out[wave] = p * (1.0f / 9.0f);
}

extern "C" void kernel_launch(void* const* d_in, const int* in_sizes, int n_in,
                              void* d_out, int out_size, void* d_ws, size_t ws_size,
                              hipStream_t stream) {
    const float* user_emb = (const float*)d_in[0];
    const float* item_emb = (const float*)d_in[1];
    const float* cat_emb  = (const float*)d_in[2];
    const float* g_vals   = (const float*)d_in[3];
    const float* gx_vals  = (const float*)d_in[4];
    const int* g_rows  = (const int*)d_in[5];
    const int* g_cols  = (const int*)d_in[6];
    const int* gx_rows = (const int*)d_in[7];
    const int* gx_cols = (const int*)d_in[8];
    const int* train_users = (const int*)d_in[9];
    const int* train_items = (const int*)d_in[10];
    const int* i2c   = (const int*)d_in[11];
    const int* users = (const int*)d_in[12];
    const int* items = (const int*)d_in[13];
    float* out = (float*)d_out;

    char* ws = (char*)d_ws;
    size_t off = 0;
    auto alloc = [&](size_t bytes) -> void* {
        void* p = ws + off;
        off += (bytes + 255) & ~(size_t)255;
        return p;
    };
    const size_t NB = (size_t)N_NODES * D * sizeof(float);   // 25.6 MB
    const size_t NBH = (size_t)N_NODES * D * sizeof(ushort); // 12.8 MB
    float*  xf   = (float*)alloc(NB);
    ushort* xb   = (ushort*)alloc(NBH);
    float*  tf   = (float*)alloc(NB);
    ushort* tb   = (ushort*)alloc(NBH);
    float*  accb = (float*)alloc(NB);
    float*  dinv = (float*)alloc((size_t)N_NODES * sizeof(float));
    int*  sbhC  = (int*)alloc((size_t)NSB * sizeof(int));
    int*  sboffC= (int*)alloc((size_t)(NSB + 1) * sizeof(int));
    int*  sbcurC= (int*)alloc((size_t)NSB * sizeof(int));
    int*  cntG  = (int*)alloc((size_t)NBKT * sizeof(int));
    int*  offG  = (int*)alloc((size_t)(NBKT + 1) * sizeof(int));
    int*  curG  = (int*)alloc((size_t)NBKT * sizeof(int));
    int*  rowC  = (int*)alloc((size_t)(N_NODES + 1) * sizeof(int));
    int*  rowG  = (int*)alloc((size_t)(N_NODES + 1) * sizeof(int));
    int2* edgeCr = (int2*)alloc((size_t)2 * NNZ_GX * sizeof(int2));
    int2* edgeCs = (int2*)alloc((size_t)2 * NNZ_GX * sizeof(int2));
    int2* edgeGr = (int2*)alloc((size_t)NNZ_G * sizeof(int2));
    int2* edgeGs = (int2*)alloc((size_t)NNZ_G * sizeof(int2));

    hipMemsetAsync(accb, 0, NB, stream);
    hipMemsetAsync(dinv, 0, (size_t)N_NODES * sizeof(float), stream);
    hipMemsetAsync(sbhC, 0, (size_t)NSB * sizeof(int), stream);
    hipMemsetAsync(cntG, 0, (size_t)NBKT * sizeof(int), stream);

    init_x_kernel<<<(N_NODES * D / 4 + 255) / 256, 256, 0, stream>>>(user_emb, item_emb, xf, xb);
    deg_kernel<<<(N_EDGES + 255) / 256, 256, 0, stream>>>(train_users, train_items, dinv);
    dinv_kernel<<<(N_NODES + 255) / 256, 256, 0, stream>>>(dinv);

    // C build
    histsb_c_kernel<<<256, 256, 0, stream>>>(gx_rows, train_users, train_items, sbhC);
    scansb_kernel<<<1, 64, 0, stream>>>(sbhC, sboffC, sbcurC, rowC + N_NODES);
    p1c_kernel<<<(NNZ_GX + P1_TILE - 1) / P1_TILE, 256, 0, stream>>>(
        gx_rows, gx_cols, gx_vals, train_users, train_items, i2c, sbcurC, edgeCr);
    p2c_kernel<<<NSB, 512, 0, stream>>>(sboffC, edgeCr, edgeCs, rowC);

    // G build
    histg_kernel<<<256, 256, 0, stream>>>(g_rows, cntG);
    scang_kernel<<<1, 1024, 0, stream>>>(cntG, offG, curG, rowG);
    append_g_kernel<<<(NNZ_G + 255) / 256, 256, 0, stream>>>(g_rows, g_cols, g_vals,
                                                             curG, edgeGr);
    sort_g_kernel<<<NBKT, 256, 0, stream>>>(offG, edgeGr, edgeGs, rowG);

    const int pull_grid = (N_NODES * 64 + 255) / 256;
    for (int layer = 0; layer < N_LAYERS; ++layer) {
        pull_g_kernel<<<pull_grid, 256, 0, stream>>>(rowG, edgeGs, xb, tf, tb);
        if (layer == 0)
            pull_c_fused<1><<<pull_grid, 256, 0, stream>>>(rowC, edgeCs, cat_emb, tb, tf,
                                                           dinv, xf, xb, accb);
        else
            pull_c_fused<0><<<pull_grid, 256, 0, stream>>>(rowC, edgeCs, cat_emb, tb, tf,
                                                           dinv, xf, xb, accb);
    }

    gamma_kernel<<<(BATCH * 64 + 255) / 256, 256, 0, stream>>>(users, items, accb, out);
}

// Round 7
// 781.103 us; speedup vs baseline: 16.6179x; 1.0962x over previous
//
#include <hip/hip_runtime.h>

#define NUM_USERS 50000
#define NUM_ITEMS 50000
#define NUM_CATS  500
#define D         64
#define N_LAYERS  3
#define N_EDGES   500000
#define NNZ_G     1000000
#define NNZ_GX    2000000
#define BATCH     8192
#define N_NODES   (NUM_USERS + NUM_ITEMS)

// G-path fine buckets
#define BKT_SHIFT 4
#define BKT_W     16
#define NBKT      (N_NODES / BKT_W)   // 6250

// C-path super-buckets
#define SB_SHIFT  9
#define SB_W      512
#define NSB       ((N_NODES + SB_W - 1) / SB_W)   // 196
#define P1_K      15
#define P1_TILE   (256 * P1_K)        // 3840 nnz per WG
#define P1_REC    (2 * P1_TILE)       // 7680 records

__device__ __forceinline__ unsigned bf16rne(float f) {
    unsigned u = __float_as_uint(f);
    return (u + 0x7FFFu + ((u >> 16) & 1u)) >> 16;
}
// unpack 8 bf16 (uint4) -> 8 f32
__device__ __forceinline__ void bf16x8_to_f8(uint4 w, float* r) {
    r[0] = __uint_as_float(w.x << 16); r[1] = __uint_as_float(w.x & 0xFFFF0000u);
    r[2] = __uint_as_float(w.y << 16); r[3] = __uint_as_float(w.y & 0xFFFF0000u);
    r[4] = __uint_as_float(w.z << 16); r[5] = __uint_as_float(w.z & 0xFFFF0000u);
    r[6] = __uint_as_float(w.w << 16); r[7] = __uint_as_float(w.w & 0xFFFF0000u);
}
__device__ __forceinline__ uint4 f8_to_bf16x8(const float* r) {
    uint4 w;
    w.x = bf16rne(r[0]) | (bf16rne(r[1]) << 16);
    w.y = bf16rne(r[2]) | (bf16rne(r[3]) << 16);
    w.z = bf16rne(r[4]) | (bf16rne(r[5]) << 16);
    w.w = bf16rne(r[6]) | (bf16rne(r[7]) << 16);
    return w;
}

// ---------- degree ----------
__global__ void deg_kernel(const int* __restrict__ tu, const int* __restrict__ ti,
                           float* __restrict__ deg) {
    int e = blockIdx.x * blockDim.x + threadIdx.x;
    if (e >= N_EDGES) return;
    unsafeAtomicAdd(deg + tu[e], 1.0f);
    unsafeAtomicAdd(deg + NUM_USERS + ti[e], 1.0f);
}

__global__ void dinv_kernel(float* __restrict__ deg) {
    int n = blockIdx.x * blockDim.x + threadIdx.x;
    if (n < N_NODES) deg[n] = 1.0f / (deg[n] + 1e-9f);
}

// ---------- init x (bf16 only) ----------
__global__ void init_x_kernel(const float* __restrict__ ue, const float* __restrict__ ie,
                              ushort* __restrict__ xb) {
    int i4 = blockIdx.x * blockDim.x + threadIdx.x;   // float4 index
    if (i4 >= N_NODES * D / 4) return;
    const int half = NUM_USERS * D / 4;
    float4 v = (i4 < half) ? ((const float4*)ue)[i4] : ((const float4*)ie)[i4 - half];
    uint2 p;
    p.x = bf16rne(v.x) | (bf16rne(v.y) << 16);
    p.y = bf16rne(v.z) | (bf16rne(v.w) << 16);
    ((uint2*)xb)[i4] = p;
}

// ---------- C: super-bucket histogram ----------
__global__ void histsb_c_kernel(const int* __restrict__ gx_rows,
                                const int* __restrict__ tu, const int* __restrict__ ti,
                                int* __restrict__ cnt) {
    __shared__ int h[NSB];
    for (int i = threadIdx.x; i < NSB; i += blockDim.x) h[i] = 0;
    __syncthreads();
    int stride = gridDim.x * blockDim.x;
    for (int j = blockIdx.x * blockDim.x + threadIdx.x; j < NNZ_GX; j += stride) {
        int r = gx_rows[j];
        atomicAdd(h + (tu[r] >> SB_SHIFT), 1);
        atomicAdd(h + ((NUM_USERS + ti[r]) >> SB_SHIFT), 1);
    }
    __syncthreads();
    for (int i = threadIdx.x; i < NSB; i += blockDim.x)
        if (h[i]) atomicAdd(cnt + i, h[i]);
}

// ---------- C: tiny scan ----------
__global__ void scansb_kernel(const int* __restrict__ cnt, int* __restrict__ off,
                              int* __restrict__ cur, int* __restrict__ row_sentinel) {
    if (threadIdx.x == 0) {
        int run = 0;
        for (int i = 0; i < NSB; ++i) { off[i] = run; cur[i] = run; run += cnt[i]; }
        off[NSB] = run;
        row_sentinel[0] = run;
    }
}

// ---------- C phase 1: WG multisplit append ----------
__global__ void __launch_bounds__(256) p1c_kernel(
        const int* __restrict__ gx_rows, const int* __restrict__ gx_cols,
        const float* __restrict__ gx_vals,
        const int* __restrict__ tu, const int* __restrict__ ti,
        const int* __restrict__ i2c,
        int* __restrict__ sbcur, int2* __restrict__ out) {
    __shared__ int2 recs[P1_REC];                 // 60 KB
    __shared__ int h[NSB], base[NSB], cur[NSB];
    int t = threadIdx.x;
    for (int i = t; i < NSB; i += 256) { h[i] = 0; cur[i] = 0; }
    __syncthreads();
    int tb = blockIdx.x * P1_TILE;
    #pragma unroll
    for (int k = 0; k < P1_K; ++k) {
        int l = t + k * 256;
        int j = tb + l;
        if (j < NNZ_GX) {
            int r = gx_rows[j], c = gx_cols[j];
            unsigned vb = bf16rne(gx_vals[j]);
            int tur = tu[r], tir = ti[r], tuc = tu[c], tic = ti[c];
            int cat = i2c[tic];
            int ylo = (int)(vb << 16) | (cat << 1);
            unsigned dstu = (unsigned)tur;           int srcu = tuc;
            unsigned dsti = (unsigned)(NUM_USERS + tir); int srci = NUM_USERS + tic;
            recs[2 * l] = make_int2((int)((dstu << 15) | (unsigned)(srcu & 0x7FFF)),
                                    ylo | (((srcu >> 15) & 3) << 10));
            recs[2 * l + 1] = make_int2((int)((dsti << 15) | (unsigned)(srci & 0x7FFF)),
                                        ylo | (((srci >> 15) & 3) << 10) | 1);
            atomicAdd(h + (int)(dstu >> SB_SHIFT), 1);
            atomicAdd(h + (int)(dsti >> SB_SHIFT), 1);
        }
    }
    __syncthreads();
    if (t < NSB) base[t] = atomicAdd(sbcur + t, h[t]);
    __syncthreads();
    int rem = NNZ_GX - tb;
    int nrec = 2 * (rem < P1_TILE ? rem : P1_TILE);
    for (int s = t; s < nrec; s += 256) {
        int2 rec = recs[s];
        int bkt = (int)(((unsigned)rec.x) >> 24);
        int p = base[bkt] + atomicAdd(cur + bkt, 1);
        out[p] = rec;
    }
}

// ---------- C phase 2: per-super-bucket node sort, emits rowC ----------
__global__ void __launch_bounds__(512) p2c_kernel(
        const int* __restrict__ sboff, const int2* __restrict__ raw,
        int2* __restrict__ sorted, int* __restrict__ rowC) {
    int b = blockIdx.x;
    int beg = sboff[b], end = sboff[b + 1];
    __shared__ int h[SB_W], cur[SB_W];
    int t = threadIdx.x;
    h[t] = 0;
    __syncthreads();
    for (int i = beg + t; i < end; i += 512)
        atomicAdd(h + (int)((((unsigned)raw[i].x) >> 15) & (SB_W - 1)), 1);
    __syncthreads();
    int cnt = h[t];
    for (int o = 1; o < SB_W; o <<= 1) {
        int tmp = (t >= o) ? h[t - o] : 0;
        __syncthreads();
        h[t] += tmp;
        __syncthreads();
    }
    int excl = h[t] - cnt;
    cur[t] = beg + excl;
    int node = b * SB_W + t;
    if (node < N_NODES) rowC[node] = beg + excl;
    __syncthreads();
    for (int i = beg + t; i < end; i += 512) {
        int2 e = raw[i];
        unsigned rx = (unsigned)e.x;
        int dl = (int)((rx >> 15) & (SB_W - 1));
        int src = (int)(rx & 0x7FFF) | (((e.y >> 10) & 3) << 15);
        int p = atomicAdd(cur + dl, 1);
        sorted[p] = make_int2((src << 10) | (e.y & 0x3FF), e.y & 0xFFFF0000);
    }
}

// ---------- G path ----------
__global__ void histg_kernel(const int* __restrict__ g_rows, int* __restrict__ cnt) {
    __shared__ int h[NBKT];
    for (int i = threadIdx.x; i < NBKT; i += blockDim.x) h[i] = 0;
    __syncthreads();
    int stride = gridDim.x * blockDim.x;
    for (int e = blockIdx.x * blockDim.x + threadIdx.x; e < NNZ_G; e += stride)
        atomicAdd(h + (g_rows[e] >> BKT_SHIFT), 1);
    __syncthreads();
    for (int i = threadIdx.x; i < NBKT; i += blockDim.x)
        if (h[i]) atomicAdd(cnt + i, h[i]);
}

__global__ void scang_kernel(const int* __restrict__ cnt, int* __restrict__ off,
                             int* __restrict__ cur, int* __restrict__ row) {
    __shared__ int sums[1024];
    const int T = 1024;
    const int strip = (NBKT + T - 1) / T;
    int t = threadIdx.x;
    int beg = t * strip;
    int end = beg + strip; if (end > NBKT) end = NBKT;
    int s = 0;
    for (int i = beg; i < end; ++i) s += cnt[i];
    sums[t] = s;
    __syncthreads();
    if (t == 0) {
        int run = 0;
        for (int i = 0; i < T; ++i) { int v = sums[i]; sums[i] = run; run += v; }
        off[NBKT] = run;
        row[N_NODES] = run;
    }
    __syncthreads();
    int run = sums[t];
    for (int i = beg; i < end; ++i) { off[i] = run; cur[i] = run; run += cnt[i]; }
}

__global__ void append_g_kernel(const int* __restrict__ g_rows, const int* __restrict__ g_cols,
                                const float* __restrict__ g_vals,
                                int* __restrict__ cur, int2* __restrict__ edges) {
    int e = blockIdx.x * blockDim.x + threadIdx.x;
    if (e >= NNZ_G) return;
    int dst = g_rows[e];
    int p = atomicAdd(cur + (dst >> BKT_SHIFT), 1);
    edges[p] = make_int2(((dst & (BKT_W - 1)) << 17) | g_cols[e], __float_as_int(g_vals[e]));
}

__global__ void sort_g_kernel(const int* __restrict__ off, const int2* __restrict__ raw,
                              int2* __restrict__ sorted, int* __restrict__ rowG) {
    int b = blockIdx.x;
    int base = off[b], end = off[b + 1];
    __shared__ int hist[BKT_W], cur[BKT_W], scn[BKT_W];
    if (threadIdx.x < BKT_W) hist[threadIdx.x] = 0;
    __syncthreads();
    for (int i = base + threadIdx.x; i < end; i += blockDim.x)
        atomicAdd(hist + ((raw[i].x >> 17) & 15), 1);
    __syncthreads();
    if (threadIdx.x == 0) {
        int run = 0;
        for (int k = 0; k < BKT_W; ++k) { scn[k] = run; cur[k] = run; run += hist[k]; }
    }
    __syncthreads();
    if (threadIdx.x < BKT_W) rowG[b * BKT_W + threadIdx.x] = base + scn[threadIdx.x];
    for (int i = base + threadIdx.x; i < end; i += blockDim.x) {
        int2 e = raw[i];
        int dl = (e.x >> 17) & 15;
        int p = atomicAdd(cur + dl, 1);
        sorted[base + p] = make_int2((e.x & 0x1FFFF) << 6, e.y);  // src*64 (element index)
    }
}

// ---------- pull SpMM (G): 8 lanes/edge, uint4 bf16 gathers, writes tb only ----------
__global__ void pull_g_kernel(const int* __restrict__ row, const int2* __restrict__ edges,
                              const ushort* __restrict__ xb, ushort* __restrict__ tb) {
    int wave = (blockIdx.x * blockDim.x + threadIdx.x) >> 6;
    int lane = threadIdx.x & 63;
    if (wave >= N_NODES) return;
    int g = lane >> 3;        // edge group 0..7
    int s = lane & 7;         // 8-elem slot within row
    int beg = row[wave], end = row[wave + 1];
    float acc[8] = {0.f, 0.f, 0.f, 0.f, 0.f, 0.f, 0.f, 0.f};
    #pragma unroll 2
    for (int i = beg + g; i < end; i += 8) {
        int2 e = edges[i];
        float v = __int_as_float(e.y);
        uint4 w = *(const uint4*)(xb + e.x + s * 8);
        float xv[8];
        bf16x8_to_f8(w, xv);
        #pragma unroll
        for (int d = 0; d < 8; ++d) acc[d] += v * xv[d];
    }
    #pragma unroll
    for (int d = 0; d < 8; ++d) {
        acc[d] += __shfl_xor(acc[d], 8, 64);
        acc[d] += __shfl_xor(acc[d], 16, 64);
        acc[d] += __shfl_xor(acc[d], 32, 64);
    }
    if (lane < 8) {
        uint4 p = f8_to_bf16x8(acc);
        *(uint4*)(tb + (size_t)wave * D + lane * 8) = p;
    }
}

// ---------- pull SpMM (C) fused with finalize: gathers bf16 t ----------
template <int LAYER0>
__global__ void pull_c_fused(const int* __restrict__ row, const int2* __restrict__ edges,
                             const float* __restrict__ catbase,
                             const ushort* __restrict__ tb,
                             const float* __restrict__ dinv,
                             ushort* __restrict__ xb, float* __restrict__ accb) {
    int wave = (blockIdx.x * blockDim.x + threadIdx.x) >> 6;
    int lane = threadIdx.x & 63;
    if (wave >= N_NODES) return;
    int g = lane >> 3;
    int s = lane & 7;
    int beg = row[wave], end = row[wave + 1];
    float acc[8] = {0.f, 0.f, 0.f, 0.f, 0.f, 0.f, 0.f, 0.f};
    #pragma unroll 2
    for (int i = beg + g; i < end; i += 8) {
        int2 e = edges[i];
        float v = __int_as_float(e.y);
        int src = e.x >> 10;
        uint4 w = *(const uint4*)(tb + (size_t)src * D + s * 8);
        float xv[8];
        bf16x8_to_f8(w, xv);
        if (LAYER0) {
            int code = e.x & 1023;  // (cat<<1)|half
            const float* cb = catbase + (code >> 1) * (2 * D) + ((code & 1) << 6) + s * 8;
            float4 c0 = *(const float4*)cb;
            float4 c1 = *(const float4*)(cb + 4);
            xv[0] += c0.x; xv[1] += c0.y; xv[2] += c0.z; xv[3] += c0.w;
            xv[4] += c1.x; xv[5] += c1.y; xv[6] += c1.z; xv[7] += c1.w;
        }
        #pragma unroll
        for (int d = 0; d < 8; ++d) acc[d] += v * xv[d];
    }
    #pragma unroll
    for (int d = 0; d < 8; ++d) {
        acc[d] += __shfl_xor(acc[d], 8, 64);
        acc[d] += __shfl_xor(acc[d], 16, 64);
        acc[d] += __shfl_xor(acc[d], 32, 64);
    }
    if (lane < 8) {
        float di = dinv[wave];
        size_t o = (size_t)wave * D + lane * 8;
        uint4 tw = *(const uint4*)(tb + o);
        float tv[8];
        bf16x8_to_f8(tw, tv);
        float nx[8];
        #pragma unroll
        for (int d = 0; d < 8; ++d) nx[d] = (acc[d] * di + tv[d]) * 0.5f;
        *(uint4*)(xb + o) = f8_to_bf16x8(nx);
        float4 a0 = *(const float4*)(accb + o);
        float4 a1 = *(const float4*)(accb + o + 4);
        a0.x += nx[0]; a0.y += nx[1]; a0.z += nx[2]; a0.w += nx[3];
        a1.x += nx[4]; a1.y += nx[5]; a1.z += nx[6]; a1.w += nx[7];
        *(float4*)(accb + o) = a0;
        *(float4*)(accb + o + 4) = a1;
    }
}

// ---------- gamma ----------
__global__ void gamma_kernel(const int* __restrict__ users, const int* __restrict__ items,
                             const float* __restrict__ acc, float* __restrict__ out) {
    int wave = (blockIdx.x * blockDim.x + threadIdx.x) >> 6;
    int lane = threadIdx.x & 63;
    if (wave >= BATCH) return;
    int u = users[wave], it = items[wave];
    float p = acc[(size_t)u * D + lane] * acc[(size_t)(NUM_USERS + it) * D + lane];
#pragma unroll
    for (int off = 32; off > 0; off >>= 1) p += __shfl_down(p, off, 64);
    if (lane == 0) out[wave] = p * (1.0f / 9.0f);
}

extern "C" void kernel_launch(void* const* d_in, const int* in_sizes, int n_in,
                              void* d_out, int out_size, void* d_ws, size_t ws_size,
                              hipStream_t stream) {
    const float* user_emb = (const float*)d_in[0];
    const float* item_emb = (const float*)d_in[1];
    const float* cat_emb  = (const float*)d_in[2];
    const float* g_vals   = (const float*)d_in[3];
    const float* gx_vals  = (const float*)d_in[4];
    const int* g_rows  = (const int*)d_in[5];
    const int* g_cols  = (const int*)d_in[6];
    const int* gx_rows = (const int*)d_in[7];
    const int* gx_cols = (const int*)d_in[8];
    const int* train_users = (const int*)d_in[9];
    const int* train_items = (const int*)d_in[10];
    const int* i2c   = (const int*)d_in[11];
    const int* users = (const int*)d_in[12];
    const int* items = (const int*)d_in[13];
    float* out = (float*)d_out;

    char* ws = (char*)d_ws;
    size_t off = 0;
    auto alloc = [&](size_t bytes) -> void* {
        void* p = ws + off;
        off += (bytes + 255) & ~(size_t)255;
        return p;
    };
    const size_t NB = (size_t)N_NODES * D * sizeof(float);   // 25.6 MB
    const size_t NBH = (size_t)N_NODES * D * sizeof(ushort); // 12.8 MB
    ushort* xb   = (ushort*)alloc(NBH);
    ushort* tb   = (ushort*)alloc(NBH);
    float*  accb = (float*)alloc(NB);
    float*  dinv = (float*)alloc((size_t)N_NODES * sizeof(float));
    int*  sbhC  = (int*)alloc((size_t)NSB * sizeof(int));
    int*  sboffC= (int*)alloc((size_t)(NSB + 1) * sizeof(int));
    int*  sbcurC= (int*)alloc((size_t)NSB * sizeof(int));
    int*  cntG  = (int*)alloc((size_t)NBKT * sizeof(int));
    int*  offG  = (int*)alloc((size_t)(NBKT + 1) * sizeof(int));
    int*  curG  = (int*)alloc((size_t)NBKT * sizeof(int));
    int*  rowC  = (int*)alloc((size_t)(N_NODES + 1) * sizeof(int));
    int*  rowG  = (int*)alloc((size_t)(N_NODES + 1) * sizeof(int));
    int2* edgeCr = (int2*)alloc((size_t)2 * NNZ_GX * sizeof(int2));
    int2* edgeCs = (int2*)alloc((size_t)2 * NNZ_GX * sizeof(int2));
    int2* edgeGr = (int2*)alloc((size_t)NNZ_G * sizeof(int2));
    int2* edgeGs = (int2*)alloc((size_t)NNZ_G * sizeof(int2));

    hipMemsetAsync(accb, 0, NB, stream);
    hipMemsetAsync(dinv, 0, (size_t)N_NODES * sizeof(float), stream);
    hipMemsetAsync(sbhC, 0, (size_t)NSB * sizeof(int), stream);
    hipMemsetAsync(cntG, 0, (size_t)NBKT * sizeof(int), stream);

    init_x_kernel<<<(N_NODES * D / 4 + 255) / 256, 256, 0, stream>>>(user_emb, item_emb, xb);
    deg_kernel<<<(N_EDGES + 255) / 256, 256, 0, stream>>>(train_users, train_items, dinv);
    dinv_kernel<<<(N_NODES + 255) / 256, 256, 0, stream>>>(dinv);

    // C build
    histsb_c_kernel<<<256, 256, 0, stream>>>(gx_rows, train_users, train_items, sbhC);
    scansb_kernel<<<1, 64, 0, stream>>>(sbhC, sboffC, sbcurC, rowC + N_NODES);
    p1c_kernel<<<(NNZ_GX + P1_TILE - 1) / P1_TILE, 256, 0, stream>>>(
        gx_rows, gx_cols, gx_vals, train_users, train_items, i2c, sbcurC, edgeCr);
    p2c_kernel<<<NSB, 512, 0, stream>>>(sboffC, edgeCr, edgeCs, rowC);

    // G build
    histg_kernel<<<256, 256, 0, stream>>>(g_rows, cntG);
    scang_kernel<<<1, 1024, 0, stream>>>(cntG, offG, curG, rowG);
    append_g_kernel<<<(NNZ_G + 255) / 256, 256, 0, stream>>>(g_rows, g_cols, g_vals,
                                                             curG, edgeGr);
    sort_g_kernel<<<NBKT, 256, 0, stream>>>(offG, edgeGr, edgeGs, rowG);

    const int pull_grid = (N_NODES * 64 + 255) / 256;
    for (int layer = 0; layer < N_LAYERS; ++layer) {
        pull_g_kernel<<<pull_grid, 256, 0, stream>>>(rowG, edgeGs, xb, tb);
        if (layer == 0)
            pull_c_fused<1><<<pull_grid, 256, 0, stream>>>(rowC, edgeCs, cat_emb, tb,
                                                           dinv, xb, accb);
        else
            pull_c_fused<0><<<pull_grid, 256, 0, stream>>>(rowC, edgeCs, cat_emb, tb,
                                                           dinv, xb, accb);
    }

    gamma_kernel<<<(BATCH * 64 + 255) / 256, 256, 0, stream>>>(users, items, accb, out);
}

// Round 8
// 714.704 us; speedup vs baseline: 18.1618x; 1.0929x over previous
//
#include <hip/hip_runtime.h>

#define NUM_USERS 50000
#define NUM_ITEMS 50000
#define NUM_CATS  500
#define D         64
#define N_LAYERS  3
#define N_EDGES   500000
#define NNZ_G     1000000
#define NNZ_GX    2000000
#define BATCH     8192
#define N_NODES   (NUM_USERS + NUM_ITEMS)

// G-path fine buckets
#define BKT_SHIFT 4
#define BKT_W     16
#define NBKT      (N_NODES / BKT_W)   // 6250

// C-path super-buckets
#define SB_SHIFT  9
#define SB_W      512
#define NSB       ((N_NODES + SB_W - 1) / SB_W)   // 196
#define P1_K      8
#define P1_TILE   (256 * P1_K)        // 2048 nnz per WG
// recs: two halves of P1_TILE int2 each => 32 KB; +3*196*4 ~= 2.3 KB => ~4 WGs/CU

__device__ __forceinline__ unsigned bf16rne(float f) {
    unsigned u = __float_as_uint(f);
    return (u + 0x7FFFu + ((u >> 16) & 1u)) >> 16;
}
__device__ __forceinline__ void bf16x8_to_f8(uint4 w, float* r) {
    r[0] = __uint_as_float(w.x << 16); r[1] = __uint_as_float(w.x & 0xFFFF0000u);
    r[2] = __uint_as_float(w.y << 16); r[3] = __uint_as_float(w.y & 0xFFFF0000u);
    r[4] = __uint_as_float(w.z << 16); r[5] = __uint_as_float(w.z & 0xFFFF0000u);
    r[6] = __uint_as_float(w.w << 16); r[7] = __uint_as_float(w.w & 0xFFFF0000u);
}
__device__ __forceinline__ uint4 f8_to_bf16x8(const float* r) {
    uint4 w;
    w.x = bf16rne(r[0]) | (bf16rne(r[1]) << 16);
    w.y = bf16rne(r[2]) | (bf16rne(r[3]) << 16);
    w.z = bf16rne(r[4]) | (bf16rne(r[5]) << 16);
    w.w = bf16rne(r[6]) | (bf16rne(r[7]) << 16);
    return w;
}

// ---------- degree ----------
__global__ void deg_kernel(const int* __restrict__ tu, const int* __restrict__ ti,
                           float* __restrict__ deg) {
    int e = blockIdx.x * blockDim.x + threadIdx.x;
    if (e >= N_EDGES) return;
    unsafeAtomicAdd(deg + tu[e], 1.0f);
    unsafeAtomicAdd(deg + NUM_USERS + ti[e], 1.0f);
}

__global__ void dinv_kernel(float* __restrict__ deg) {
    int n = blockIdx.x * blockDim.x + threadIdx.x;
    if (n < N_NODES) deg[n] = 1.0f / (deg[n] + 1e-9f);
}

// ---------- init x (bf16 only) ----------
__global__ void init_x_kernel(const float* __restrict__ ue, const float* __restrict__ ie,
                              ushort* __restrict__ xb) {
    int i4 = blockIdx.x * blockDim.x + threadIdx.x;
    if (i4 >= N_NODES * D / 4) return;
    const int half = NUM_USERS * D / 4;
    float4 v = (i4 < half) ? ((const float4*)ue)[i4] : ((const float4*)ie)[i4 - half];
    uint2 p;
    p.x = bf16rne(v.x) | (bf16rne(v.y) << 16);
    p.y = bf16rne(v.z) | (bf16rne(v.w) << 16);
    ((uint2*)xb)[i4] = p;
}

// ---------- C: super-bucket histogram ----------
__global__ void histsb_c_kernel(const int* __restrict__ gx_rows,
                                const int* __restrict__ tu, const int* __restrict__ ti,
                                int* __restrict__ cnt) {
    __shared__ int h[NSB];
    for (int i = threadIdx.x; i < NSB; i += blockDim.x) h[i] = 0;
    __syncthreads();
    int stride = gridDim.x * blockDim.x;
    for (int j = blockIdx.x * blockDim.x + threadIdx.x; j < NNZ_GX; j += stride) {
        int r = gx_rows[j];
        atomicAdd(h + (tu[r] >> SB_SHIFT), 1);
        atomicAdd(h + ((NUM_USERS + ti[r]) >> SB_SHIFT), 1);
    }
    __syncthreads();
    for (int i = threadIdx.x; i < NSB; i += blockDim.x)
        if (h[i]) atomicAdd(cnt + i, h[i]);
}

// ---------- C: tiny scan ----------
__global__ void scansb_kernel(const int* __restrict__ cnt, int* __restrict__ off,
                              int* __restrict__ cur, int* __restrict__ row_sentinel) {
    if (threadIdx.x == 0) {
        int run = 0;
        for (int i = 0; i < NSB; ++i) { off[i] = run; cur[i] = run; run += cnt[i]; }
        off[NSB] = run;
        row_sentinel[0] = run;
    }
}

// ---------- C phase 1: WG multisplit append (SoA recs, small tile) ----------
__global__ void __launch_bounds__(256) p1c_kernel(
        const int* __restrict__ gx_rows, const int* __restrict__ gx_cols,
        const float* __restrict__ gx_vals,
        const int* __restrict__ tu, const int* __restrict__ ti,
        const int* __restrict__ i2c,
        int* __restrict__ sbcur, int2* __restrict__ out) {
    __shared__ int2 recs[2 * P1_TILE];            // 32 KB, two halves
    __shared__ int h[NSB], base[NSB], cur[NSB];
    int t = threadIdx.x;
    for (int i = t; i < NSB; i += 256) { h[i] = 0; cur[i] = 0; }
    __syncthreads();
    int tb = blockIdx.x * P1_TILE;
    #pragma unroll
    for (int k = 0; k < P1_K; ++k) {
        int l = t + k * 256;
        int j = tb + l;
        if (j < NNZ_GX) {
            int r = gx_rows[j], c = gx_cols[j];
            unsigned vb = bf16rne(gx_vals[j]);
            int tur = tu[r], tir = ti[r], tuc = tu[c], tic = ti[c];
            int cat = i2c[tic];
            int ylo = (int)(vb << 16) | (cat << 1);
            unsigned dstu = (unsigned)tur;           int srcu = tuc;
            unsigned dsti = (unsigned)(NUM_USERS + tir); int srci = NUM_USERS + tic;
            recs[l] = make_int2((int)((dstu << 15) | (unsigned)(srcu & 0x7FFF)),
                                ylo | (((srcu >> 15) & 3) << 10));
            recs[P1_TILE + l] = make_int2((int)((dsti << 15) | (unsigned)(srci & 0x7FFF)),
                                          ylo | (((srci >> 15) & 3) << 10) | 1);
            atomicAdd(h + (int)(dstu >> SB_SHIFT), 1);
            atomicAdd(h + (int)(dsti >> SB_SHIFT), 1);
        }
    }
    __syncthreads();
    if (t < NSB) base[t] = atomicAdd(sbcur + t, h[t]);
    __syncthreads();
    int rem = NNZ_GX - tb;
    int nv = rem < P1_TILE ? rem : P1_TILE;
    for (int s = t; s < nv; s += 256) {
        int2 rec = recs[s];
        int bkt = (int)(((unsigned)rec.x) >> 24);
        int p = base[bkt] + atomicAdd(cur + bkt, 1);
        out[p] = rec;
        rec = recs[P1_TILE + s];
        bkt = (int)(((unsigned)rec.x) >> 24);
        p = base[bkt] + atomicAdd(cur + bkt, 1);
        out[p] = rec;
    }
}

// ---------- C phase 2: per-super-bucket node sort, emits rowC ----------
__global__ void __launch_bounds__(512) p2c_kernel(
        const int* __restrict__ sboff, const int2* __restrict__ raw,
        int2* __restrict__ sorted, int* __restrict__ rowC) {
    int b = blockIdx.x;
    int beg = sboff[b], end = sboff[b + 1];
    __shared__ int h[SB_W], cur[SB_W];
    int t = threadIdx.x;
    h[t] = 0;
    __syncthreads();
    for (int i = beg + t; i < end; i += 512)
        atomicAdd(h + (int)((((unsigned)raw[i].x) >> 15) & (SB_W - 1)), 1);
    __syncthreads();
    int cnt = h[t];
    for (int o = 1; o < SB_W; o <<= 1) {
        int tmp = (t >= o) ? h[t - o] : 0;
        __syncthreads();
        h[t] += tmp;
        __syncthreads();
    }
    int excl = h[t] - cnt;
    cur[t] = beg + excl;
    int node = b * SB_W + t;
    if (node < N_NODES) rowC[node] = beg + excl;
    __syncthreads();
    for (int i = beg + t; i < end; i += 512) {
        int2 e = raw[i];
        unsigned rx = (unsigned)e.x;
        int dl = (int)((rx >> 15) & (SB_W - 1));
        int src = (int)(rx & 0x7FFF) | (((e.y >> 10) & 3) << 15);
        int p = atomicAdd(cur + dl, 1);
        sorted[p] = make_int2((src << 10) | (e.y & 0x3FF), e.y & 0xFFFF0000);
    }
}

// ---------- G path ----------
__global__ void histg_kernel(const int* __restrict__ g_rows, int* __restrict__ cnt) {
    __shared__ int h[NBKT];
    for (int i = threadIdx.x; i < NBKT; i += blockDim.x) h[i] = 0;
    __syncthreads();
    int stride = gridDim.x * blockDim.x;
    for (int e = blockIdx.x * blockDim.x + threadIdx.x; e < NNZ_G; e += stride)
        atomicAdd(h + (g_rows[e] >> BKT_SHIFT), 1);
    __syncthreads();
    for (int i = threadIdx.x; i < NBKT; i += blockDim.x)
        if (h[i]) atomicAdd(cnt + i, h[i]);
}

__global__ void scang_kernel(const int* __restrict__ cnt, int* __restrict__ off,
                             int* __restrict__ cur, int* __restrict__ row) {
    __shared__ int sums[1024];
    const int T = 1024;
    const int strip = (NBKT + T - 1) / T;
    int t = threadIdx.x;
    int beg = t * strip;
    int end = beg + strip; if (end > NBKT) end = NBKT;
    int s = 0;
    for (int i = beg; i < end; ++i) s += cnt[i];
    sums[t] = s;
    __syncthreads();
    if (t == 0) {
        int run = 0;
        for (int i = 0; i < T; ++i) { int v = sums[i]; sums[i] = run; run += v; }
        off[NBKT] = run;
        row[N_NODES] = run;
    }
    __syncthreads();
    int run = sums[t];
    for (int i = beg; i < end; ++i) { off[i] = run; cur[i] = run; run += cnt[i]; }
}

__global__ void append_g_kernel(const int* __restrict__ g_rows, const int* __restrict__ g_cols,
                                const float* __restrict__ g_vals,
                                int* __restrict__ cur, int2* __restrict__ edges) {
    int e = blockIdx.x * blockDim.x + threadIdx.x;
    if (e >= NNZ_G) return;
    int dst = g_rows[e];
    int p = atomicAdd(cur + (dst >> BKT_SHIFT), 1);
    edges[p] = make_int2(((dst & (BKT_W - 1)) << 17) | g_cols[e], __float_as_int(g_vals[e]));
}

__global__ void sort_g_kernel(const int* __restrict__ off, const int2* __restrict__ raw,
                              int2* __restrict__ sorted, int* __restrict__ rowG) {
    int b = blockIdx.x;
    int base = off[b], end = off[b + 1];
    __shared__ int hist[BKT_W], cur[BKT_W], scn[BKT_W];
    if (threadIdx.x < BKT_W) hist[threadIdx.x] = 0;
    __syncthreads();
    for (int i = base + threadIdx.x; i < end; i += blockDim.x)
        atomicAdd(hist + ((raw[i].x >> 17) & 15), 1);
    __syncthreads();
    if (threadIdx.x == 0) {
        int run = 0;
        for (int k = 0; k < BKT_W; ++k) { scn[k] = run; cur[k] = run; run += hist[k]; }
    }
    __syncthreads();
    if (threadIdx.x < BKT_W) rowG[b * BKT_W + threadIdx.x] = base + scn[threadIdx.x];
    for (int i = base + threadIdx.x; i < end; i += blockDim.x) {
        int2 e = raw[i];
        int dl = (e.x >> 17) & 15;
        int p = atomicAdd(cur + dl, 1);
        sorted[base + p] = make_int2((e.x & 0x1FFFF) << 6, e.y);  // src*64
    }
}

// ---------- pull SpMM (G): one 32-lane half-wave per node, 8 lanes/edge ----------
__global__ void pull_g_kernel(const int* __restrict__ row, const int2* __restrict__ edges,
                              const ushort* __restrict__ xb, ushort* __restrict__ tb) {
    int node = (blockIdx.x * blockDim.x + threadIdx.x) >> 5;
    int l32 = threadIdx.x & 31;
    if (node >= N_NODES) return;
    int g = l32 >> 3;         // edge group 0..3
    int s = l32 & 7;          // 8-elem slot within row
    int beg = row[node], end = row[node + 1];
    float acc[8] = {0.f, 0.f, 0.f, 0.f, 0.f, 0.f, 0.f, 0.f};
    #pragma unroll 2
    for (int i = beg + g; i < end; i += 4) {
        int2 e = edges[i];
        float v = __int_as_float(e.y);
        uint4 w = *(const uint4*)(xb + e.x + s * 8);
        float xv[8];
        bf16x8_to_f8(w, xv);
        #pragma unroll
        for (int d = 0; d < 8; ++d) acc[d] += v * xv[d];
    }
    #pragma unroll
    for (int d = 0; d < 8; ++d) {
        acc[d] += __shfl_xor(acc[d], 8, 64);
        acc[d] += __shfl_xor(acc[d], 16, 64);
    }
    if (l32 < 8) {
        uint4 p = f8_to_bf16x8(acc);
        *(uint4*)(tb + (size_t)node * D + s * 8) = p;
    }
}

// ---------- pull SpMM (C) fused with finalize: half-wave per node ----------
template <int LAYER0>
__global__ void pull_c_fused(const int* __restrict__ row, const int2* __restrict__ edges,
                             const float* __restrict__ catbase,
                             const ushort* __restrict__ tb,
                             const float* __restrict__ dinv,
                             ushort* __restrict__ xb, float* __restrict__ accb) {
    int node = (blockIdx.x * blockDim.x + threadIdx.x) >> 5;
    int l32 = threadIdx.x & 31;
    if (node >= N_NODES) return;
    int g = l32 >> 3;
    int s = l32 & 7;
    int beg = row[node], end = row[node + 1];
    float acc[8] = {0.f, 0.f, 0.f, 0.f, 0.f, 0.f, 0.f, 0.f};
    #pragma unroll 2
    for (int i = beg + g; i < end; i += 4) {
        int2 e = edges[i];
        float v = __int_as_float(e.y);
        int src = e.x >> 10;
        uint4 w = *(const uint4*)(tb + (size_t)src * D + s * 8);
        float xv[8];
        bf16x8_to_f8(w, xv);
        if (LAYER0) {
            int code = e.x & 1023;  // (cat<<1)|half
            const float* cb = catbase + (code >> 1) * (2 * D) + ((code & 1) << 6) + s * 8;
            float4 c0 = *(const float4*)cb;
            float4 c1 = *(const float4*)(cb + 4);
            xv[0] += c0.x; xv[1] += c0.y; xv[2] += c0.z; xv[3] += c0.w;
            xv[4] += c1.x; xv[5] += c1.y; xv[6] += c1.z; xv[7] += c1.w;
        }
        #pragma unroll
        for (int d = 0; d < 8; ++d) acc[d] += v * xv[d];
    }
    #pragma unroll
    for (int d = 0; d < 8; ++d) {
        acc[d] += __shfl_xor(acc[d], 8, 64);
        acc[d] += __shfl_xor(acc[d], 16, 64);
    }
    if (l32 < 8) {
        float di = dinv[node];
        size_t o = (size_t)node * D + s * 8;
        uint4 tw = *(const uint4*)(tb + o);
        float tv[8];
        bf16x8_to_f8(tw, tv);
        float nx[8];
        #pragma unroll
        for (int d = 0; d < 8; ++d) nx[d] = (acc[d] * di + tv[d]) * 0.5f;
        *(uint4*)(xb + o) = f8_to_bf16x8(nx);
        float4 a0 = *(const float4*)(accb + o);
        float4 a1 = *(const float4*)(accb + o + 4);
        a0.x += nx[0]; a0.y += nx[1]; a0.z += nx[2]; a0.w += nx[3];
        a1.x += nx[4]; a1.y += nx[5]; a1.z += nx[6]; a1.w += nx[7];
        *(float4*)(accb + o) = a0;
        *(float4*)(accb + o + 4) = a1;
    }
}

// ---------- gamma ----------
__global__ void gamma_kernel(const int* __restrict__ users, const int* __restrict__ items,
                             const float* __restrict__ acc, float* __restrict__ out) {
    int wave = (blockIdx.x * blockDim.x + threadIdx.x) >> 6;
    int lane = threadIdx.x & 63;
    if (wave >= BATCH) return;
    int u = users[wave], it = items[wave];
    float p = acc[(size_t)u * D + lane] * acc[(size_t)(NUM_USERS + it) * D + lane];
#pragma unroll
    for (int off = 32; off > 0; off >>= 1) p += __shfl_down(p, off, 64);
    if (lane == 0) out[wave] = p * (1.0f / 9.0f);
}

extern "C" void kernel_launch(void* const* d_in, const int* in_sizes, int n_in,
                              void* d_out, int out_size, void* d_ws, size_t ws_size,
                              hipStream_t stream) {
    const float* user_emb = (const float*)d_in[0];
    const float* item_emb = (const float*)d_in[1];
    const float* cat_emb  = (const float*)d_in[2];
    const float* g_vals   = (const float*)d_in[3];
    const float* gx_vals  = (const float*)d_in[4];
    const int* g_rows  = (const int*)d_in[5];
    const int* g_cols  = (const int*)d_in[6];
    const int* gx_rows = (const int*)d_in[7];
    const int* gx_cols = (const int*)d_in[8];
    const int* train_users = (const int*)d_in[9];
    const int* train_items = (const int*)d_in[10];
    const int* i2c   = (const int*)d_in[11];
    const int* users = (const int*)d_in[12];
    const int* items = (const int*)d_in[13];
    float* out = (float*)d_out;

    char* ws = (char*)d_ws;
    size_t off = 0;
    auto alloc = [&](size_t bytes) -> void* {
        void* p = ws + off;
        off += (bytes + 255) & ~(size_t)255;
        return p;
    };
    const size_t NB = (size_t)N_NODES * D * sizeof(float);   // 25.6 MB
    const size_t NBH = (size_t)N_NODES * D * sizeof(ushort); // 12.8 MB
    ushort* xb   = (ushort*)alloc(NBH);
    ushort* tb   = (ushort*)alloc(NBH);
    float*  accb = (float*)alloc(NB);
    float*  dinv = (float*)alloc((size_t)N_NODES * sizeof(float));
    int*  sbhC  = (int*)alloc((size_t)NSB * sizeof(int));
    int*  sboffC= (int*)alloc((size_t)(NSB + 1) * sizeof(int));
    int*  sbcurC= (int*)alloc((size_t)NSB * sizeof(int));
    int*  cntG  = (int*)alloc((size_t)NBKT * sizeof(int));
    int*  offG  = (int*)alloc((size_t)(NBKT + 1) * sizeof(int));
    int*  curG  = (int*)alloc((size_t)NBKT * sizeof(int));
    int*  rowC  = (int*)alloc((size_t)(N_NODES + 1) * sizeof(int));
    int*  rowG  = (int*)alloc((size_t)(N_NODES + 1) * sizeof(int));
    int2* edgeCr = (int2*)alloc((size_t)2 * NNZ_GX * sizeof(int2));
    int2* edgeCs = (int2*)alloc((size_t)2 * NNZ_GX * sizeof(int2));
    int2* edgeGr = (int2*)alloc((size_t)NNZ_G * sizeof(int2));
    int2* edgeGs = (int2*)alloc((size_t)NNZ_G * sizeof(int2));

    hipMemsetAsync(accb, 0, NB, stream);
    hipMemsetAsync(dinv, 0, (size_t)N_NODES * sizeof(float), stream);
    hipMemsetAsync(sbhC, 0, (size_t)NSB * sizeof(int), stream);
    hipMemsetAsync(cntG, 0, (size_t)NBKT * sizeof(int), stream);

    init_x_kernel<<<(N_NODES * D / 4 + 255) / 256, 256, 0, stream>>>(user_emb, item_emb, xb);
    deg_kernel<<<(N_EDGES + 255) / 256, 256, 0, stream>>>(train_users, train_items, dinv);
    dinv_kernel<<<(N_NODES + 255) / 256, 256, 0, stream>>>(dinv);

    // C build
    histsb_c_kernel<<<256, 256, 0, stream>>>(gx_rows, train_users, train_items, sbhC);
    scansb_kernel<<<1, 64, 0, stream>>>(sbhC, sboffC, sbcurC, rowC + N_NODES);
    p1c_kernel<<<(NNZ_GX + P1_TILE - 1) / P1_TILE, 256, 0, stream>>>(
        gx_rows, gx_cols, gx_vals, train_users, train_items, i2c, sbcurC, edgeCr);
    p2c_kernel<<<NSB, 512, 0, stream>>>(sboffC, edgeCr, edgeCs, rowC);

    // G build
    histg_kernel<<<256, 256, 0, stream>>>(g_rows, cntG);
    scang_kernel<<<1, 1024, 0, stream>>>(cntG, offG, curG, rowG);
    append_g_kernel<<<(NNZ_G + 255) / 256, 256, 0, stream>>>(g_rows, g_cols, g_vals,
                                                             curG, edgeGr);
    sort_g_kernel<<<NBKT, 256, 0, stream>>>(offG, edgeGr, edgeGs, rowG);

    const int pull_grid = (N_NODES * 32 + 255) / 256;
    for (int layer = 0; layer < N_LAYERS; ++layer) {
        pull_g_kernel<<<pull_grid, 256, 0, stream>>>(rowG, edgeGs, xb, tb);
        if (layer == 0)
            pull_c_fused<1><<<pull_grid, 256, 0, stream>>>(rowC, edgeCs, cat_emb, tb,
                                                           dinv, xb, accb);
        else
            pull_c_fused<0><<<pull_grid, 256, 0, stream>>>(rowC, edgeCs, cat_emb, tb,
                                                           dinv, xb, accb);
    }

    gamma_kernel<<<(BATCH * 64 + 255) / 256, 256, 0, stream>>>(users, items, accb, out);
}